// Round 1
// baseline (1237.148 us; speedup 1.0000x reference)
//
#include <hip/hip_runtime.h>
#include <cstddef>

#define BQ    16
#define CC    384
#define C3    1152
#define HH    56
#define HWP   3136
#define NHEAD 12
#define HD    32
#define WSZ   7
#define NWIN  64
#define WSQ   49
#define DKS   0.17677669529663687f

// ---------------------------------------------------------------------------
// K1/K4: roll (shift folded into indexing) + depthwise 3x3 conv, padding
// applied AFTER the roll.  rolled[i] = in[(i + shift) mod 56].
// One block per (b,c) plane; plane staged in LDS.
// ---------------------------------------------------------------------------
__global__ __launch_bounds__(256) void roll_dconv(const float* __restrict__ in,
                                                  const float* __restrict__ dw,
                                                  float* __restrict__ out,
                                                  int shift) {
    __shared__ float pl[HWP];
    __shared__ float wl[9];
    const int bc = blockIdx.x;            // b*CC + c
    const int c  = bc % CC;
    const float* src = in  + (size_t)bc * HWP;
    float*       dst = out + (size_t)bc * HWP;

    for (int i4 = threadIdx.x; i4 < HWP / 4; i4 += 256)
        ((float4*)pl)[i4] = ((const float4*)src)[i4];
    if (threadIdx.x < 9) wl[threadIdx.x] = dw[c * 9 + threadIdx.x];
    __syncthreads();

    for (int idx = threadIdx.x; idx < HWP; idx += 256) {
        const int i = idx / HH, j = idx % HH;
        float s = 0.f;
        #pragma unroll
        for (int di = 0; di < 3; ++di) {
            const int oi = i + di - 1;
            if (oi < 0 || oi >= HH) continue;
            int ri = oi + shift;
            if (ri >= HH) ri -= HH;
            if (ri < 0)   ri += HH;
            #pragma unroll
            for (int dj = 0; dj < 3; ++dj) {
                const int oj = j + dj - 1;
                if (oj < 0 || oj >= HH) continue;
                int rj = oj + shift;
                if (rj >= HH) rj -= HH;
                if (rj < 0)   rj += HH;
                s += wl[di * 3 + dj] * pl[ri * HH + rj];
            }
        }
        dst[idx] = s;
    }
}

// ---------------------------------------------------------------------------
// Transpose pointwise weights (OC,IC) -> (IC,OC) so GEMM staging is coalesced.
// ---------------------------------------------------------------------------
__global__ void transpose_w(const float* __restrict__ w, float* __restrict__ wt,
                            int OC, int IC) {
    const int idx = blockIdx.x * blockDim.x + threadIdx.x;
    if (idx >= OC * IC) return;
    const int ic = idx / OC, oc = idx % OC;
    wt[idx] = w[oc * IC + ic];
}

// ---------------------------------------------------------------------------
// K2/K5: 1x1 conv as GEMM.  OUT[b][oc][p] = sum_ic WT[ic][oc]*IN[b][ic][p] + bias
// 64(oc) x 64(p) tile per block, K-panels of 16 in LDS, 4x4 accum per thread.
// ---------------------------------------------------------------------------
template <int OC>
__global__ __launch_bounds__(256) void pconv(const float* __restrict__ in,
                                             const float* __restrict__ wt,
                                             const float* __restrict__ bias,
                                             float* __restrict__ out) {
    __shared__ float sI[16][64];
    __shared__ float sW[16][64];
    const int b   = blockIdx.z;
    const int p0  = blockIdx.x * 64;
    const int oc0 = blockIdx.y * 64;
    const int t   = threadIdx.x;
    const int tx  = t & 15, ty = t >> 4;
    const int lp  = t & 63, lk = t >> 6;      // staging lane / row

    float acc[4][4] = {};
    const float* inb = in + (size_t)b * CC * HWP;

    for (int ic0 = 0; ic0 < CC; ic0 += 16) {
        #pragma unroll
        for (int r = 0; r < 4; ++r) {
            const int kk = lk + r * 4;
            sI[kk][lp] = inb[(size_t)(ic0 + kk) * HWP + p0 + lp];
            sW[kk][lp] = wt[(size_t)(ic0 + kk) * OC + oc0 + lp];
        }
        __syncthreads();
        #pragma unroll
        for (int kk = 0; kk < 16; ++kk) {
            const float4 av = *(const float4*)&sW[kk][ty * 4];
            const float4 bv = *(const float4*)&sI[kk][tx * 4];
            acc[0][0] += av.x * bv.x; acc[0][1] += av.x * bv.y;
            acc[0][2] += av.x * bv.z; acc[0][3] += av.x * bv.w;
            acc[1][0] += av.y * bv.x; acc[1][1] += av.y * bv.y;
            acc[1][2] += av.y * bv.z; acc[1][3] += av.y * bv.w;
            acc[2][0] += av.z * bv.x; acc[2][1] += av.z * bv.y;
            acc[2][2] += av.z * bv.z; acc[2][3] += av.z * bv.w;
            acc[3][0] += av.w * bv.x; acc[3][1] += av.w * bv.y;
            acc[3][2] += av.w * bv.z; acc[3][3] += av.w * bv.w;
        }
        __syncthreads();
    }
    #pragma unroll
    for (int i = 0; i < 4; ++i) {
        const float bs = bias[oc0 + ty * 4 + i];
        float4 o;
        o.x = acc[i][0] + bs; o.y = acc[i][1] + bs;
        o.z = acc[i][2] + bs; o.w = acc[i][3] + bs;
        *(float4*)&out[((size_t)b * OC + oc0 + ty * 4 + i) * HWP + p0 + tx * 4] = o;
    }
}

// ---------------------------------------------------------------------------
// K3: windowed attention.  One block per (b, head, window).
// qkv layout: (B, 3*CC, 56, 56); q = ch[0,384), k = [384,768), v = [768,1152).
// Window w=(wr,wc): rows wr*7..+6, cols wc*7..+6; pos p=(pr*7+pc); ch=h*32+d.
// Shift mask (analytic): wr==7 masks (pr>=4)!=(pr'>=4); wc==7 likewise on pc.
// ---------------------------------------------------------------------------
__global__ __launch_bounds__(256) void attn_win(const float* __restrict__ qkv,
                                                const float* __restrict__ pos,
                                                float* __restrict__ out) {
    __shared__ float sQ[HD][WSQ];
    __shared__ float sK[HD][WSQ];
    __shared__ float sV[HD][WSQ];
    __shared__ float sS[WSQ][WSQ];
    __shared__ float sP[169];

    const int w = blockIdx.x, h = blockIdx.y, b = blockIdx.z;
    const int wr = w >> 3, wc = w & 7;
    const int t = threadIdx.x;
    if (t < 169) sP[t] = pos[t];

    const size_t baseq = ((size_t)b * C3 + h * HD) * HWP;
    for (int e = t; e < HD * WSQ; e += 256) {
        const int d = e / WSQ, p = e - d * WSQ;
        const int pr = p / WSZ, pc = p - pr * WSZ;
        const size_t off = (size_t)d * HWP + (wr * WSZ + pr) * HH + wc * WSZ + pc;
        sQ[d][p] = qkv[baseq + off];
        sK[d][p] = qkv[baseq + (size_t)CC * HWP + off];
        sV[d][p] = qkv[baseq + (size_t)2 * CC * HWP + off];
    }
    __syncthreads();

    for (int e = t; e < WSQ * WSQ; e += 256) {
        const int i = e / WSQ, j = e - i * WSQ;
        float s = 0.f;
        #pragma unroll
        for (int d = 0; d < HD; ++d) s += sQ[d][i] * sK[d][j];
        const int pir = i / WSZ, pic = i - pir * WSZ;
        const int pjr = j / WSZ, pjc = j - pjr * WSZ;
        s = s * DKS + sP[(pjr - pir + 6) * 13 + (pjc - pic + 6)];
        const bool m = (wr == 7 && ((pir >= 4) != (pjr >= 4))) ||
                       (wc == 7 && ((pic >= 4) != (pjc >= 4)));
        sS[i][j] = m ? -1e30f : s;
    }
    __syncthreads();

    if (t < WSQ) {
        float mx = -1e30f;
        for (int j = 0; j < WSQ; ++j) mx = fmaxf(mx, sS[t][j]);
        float sum = 0.f;
        for (int j = 0; j < WSQ; ++j) {
            const float e2 = __expf(sS[t][j] - mx);
            sS[t][j] = e2;
            sum += e2;
        }
        const float inv = 1.f / sum;
        for (int j = 0; j < WSQ; ++j) sS[t][j] *= inv;
    }
    __syncthreads();

    for (int e = t; e < HD * WSQ; e += 256) {
        const int d = e / WSQ, p = e - d * WSQ;
        float s = 0.f;
        #pragma unroll 7
        for (int j = 0; j < WSQ; ++j) s += sS[p][j] * sV[d][j];
        const int pr = p / WSZ, pc = p - pr * WSZ;
        out[((size_t)b * CC + h * HD + d) * HWP + (wr * WSZ + pr) * HH + wc * WSZ + pc] = s;
    }
}

// ---------------------------------------------------------------------------
extern "C" void kernel_launch(void* const* d_in, const int* in_sizes, int n_in,
                              void* d_out, int out_size, void* d_ws, size_t ws_size,
                              hipStream_t stream) {
    const float* x       = (const float*)d_in[0];
    const float* qkv_dw  = (const float*)d_in[1];
    const float* qkv_pw  = (const float*)d_in[2];
    const float* qkv_pb  = (const float*)d_in[3];
    const float* out_dw  = (const float*)d_in[4];
    const float* out_pw  = (const float*)d_in[5];
    const float* out_pb  = (const float*)d_in[6];
    const float* pos     = (const float*)d_in[7];
    float* out = (float*)d_out;
    float* ws  = (float*)d_ws;

    // ws layout: qkv (16*1152*3136 f32 = 231 MB) | wt1 (1152*384) | wt2 (384*384)
    float* qkv = ws;
    float* wt1 = ws + (size_t)BQ * C3 * HWP;
    float* wt2 = wt1 + (size_t)C3 * CC;
    float* tmp = out;   // d_out doubles as the 77 MB temp; fully overwritten by K5

    transpose_w<<<dim3((C3 * CC + 255) / 256), 256, 0, stream>>>(qkv_pw, wt1, C3, CC);
    transpose_w<<<dim3((CC * CC + 255) / 256), 256, 0, stream>>>(out_pw, wt2, CC, CC);

    // 1) roll(-3,-3) + depthwise 3x3  -> tmp (=d_out)
    roll_dconv<<<dim3(BQ * CC), 256, 0, stream>>>(x, qkv_dw, tmp, 3);
    // 2) pointwise 384 -> 1152 (+bias) -> qkv (ws)
    pconv<C3><<<dim3(HWP / 64, C3 / 64, BQ), 256, 0, stream>>>(tmp, wt1, qkv_pb, qkv);
    // 3) window attention -> tmp (=d_out, NCHW)
    attn_win<<<dim3(NWIN, NHEAD, BQ), 256, 0, stream>>>(qkv, pos, tmp);
    // 4) roll(+3,+3) + depthwise 3x3 -> ws (reuse qkv q-region)
    roll_dconv<<<dim3(BQ * CC), 256, 0, stream>>>(tmp, out_dw, ws, -3);
    // 5) pointwise 384 -> 384 (+bias) -> d_out
    pconv<CC><<<dim3(HWP / 64, CC / 64, BQ), 256, 0, stream>>>(ws, wt2, out_pb, out);
}

// Round 3
// 567.556 us; speedup vs baseline: 2.1798x; 2.1798x over previous
//
#include <hip/hip_runtime.h>
#include <hip/hip_bf16.h>
#include <cstddef>
#include <cstdint>

#define BQ    16
#define CC    384
#define C3    1152
#define HH    56
#define HWP   3136
#define NTOT  (BQ * HWP)   // 50176
#define NHEAD 12
#define HD    32
#define WSZ   7
#define NWIN  64
#define WSQ   49
#define DKS   0.17677669529663687f

typedef __attribute__((ext_vector_type(8))) short bf16x8;
typedef __attribute__((ext_vector_type(4))) float f32x4;

__device__ __forceinline__ ushort f2b(float f) {
    __hip_bfloat16 h = __float2bfloat16(f);
    return *reinterpret_cast<ushort*>(&h);
}
__device__ __forceinline__ float b2f(ushort u) {
    __hip_bfloat16 h;
    *reinterpret_cast<ushort*>(&h) = u;
    return __bfloat162float(h);
}

__global__ void cvt_bf16(const float* __restrict__ in, ushort* __restrict__ out, int n) {
    const int i = blockIdx.x * 256 + threadIdx.x;
    if (i < n) out[i] = f2b(in[i]);
}

// ---------------------------------------------------------------------------
// roll + depthwise 3x3.  Input either fp32 [b][c][p] or bf16 [c][b][p];
// output bf16 [c][b][p] (k-major for the GEMM transpose).
// ---------------------------------------------------------------------------
template <bool BF16IN, bool CMAJ>
__global__ __launch_bounds__(256) void roll_dconv(const void* __restrict__ inv,
                                                  const float* __restrict__ dw,
                                                  ushort* __restrict__ out,
                                                  int shift) {
    __shared__ __align__(16) float pl[HWP];
    __shared__ float wl[9];
    const int bc = blockIdx.x;
    const int b = bc / CC, c = bc % CC;
    const size_t inPlane  = CMAJ ? ((size_t)c * BQ + b) : ((size_t)b * CC + c);
    const size_t outPlane = (size_t)c * BQ + b;
    const int t = threadIdx.x;

    if (BF16IN) {
        const ushort* src = (const ushort*)inv + inPlane * HWP;
        for (int i = t; i < HWP / 8; i += 256) {
            uint4 raw = ((const uint4*)src)[i];
            const ushort* u = (const ushort*)&raw;
            #pragma unroll
            for (int j = 0; j < 8; ++j) pl[i * 8 + j] = b2f(u[j]);
        }
    } else {
        const float* src = (const float*)inv + inPlane * HWP;
        for (int i = t; i < HWP / 4; i += 256)
            ((float4*)pl)[i] = ((const float4*)src)[i];
    }
    if (t < 9) wl[t] = dw[c * 9 + t];
    __syncthreads();

    ushort* dst = out + outPlane * HWP;
    for (int idx = t; idx < HWP; idx += 256) {
        const int i = idx / HH, j = idx % HH;
        float s = 0.f;
        #pragma unroll
        for (int di = 0; di < 3; ++di) {
            const int oi = i + di - 1;
            if (oi < 0 || oi >= HH) continue;
            int ri = oi + shift;
            if (ri >= HH) ri -= HH;
            if (ri < 0)   ri += HH;
            #pragma unroll
            for (int dj = 0; dj < 3; ++dj) {
                const int oj = j + dj - 1;
                if (oj < 0 || oj >= HH) continue;
                int rj = oj + shift;
                if (rj >= HH) rj -= HH;
                if (rj < 0)   rj += HH;
                s += wl[di * 3 + dj] * pl[ri * HH + rj];
            }
        }
        dst[idx] = f2b(s);
    }
}

// ---------------------------------------------------------------------------
// [384][50176] bf16 -> [50176][384] bf16.  4x4 register blocklets, vector LDS.
// ---------------------------------------------------------------------------
__global__ __launch_bounds__(256) void transpose_nk(const ushort* __restrict__ in,
                                                    ushort* __restrict__ out) {
    __shared__ __align__(16) ushort sT[64][72];
    const int nt = blockIdx.x * 64, kt = blockIdx.y * 64;
    const int t = threadIdx.x;
    const int kl = (t >> 4) * 4, nl = (t & 15) * 4;
    const ushort4 r0 = *(const ushort4*)&in[(size_t)(kt + kl + 0) * NTOT + nt + nl];
    const ushort4 r1 = *(const ushort4*)&in[(size_t)(kt + kl + 1) * NTOT + nt + nl];
    const ushort4 r2 = *(const ushort4*)&in[(size_t)(kt + kl + 2) * NTOT + nt + nl];
    const ushort4 r3 = *(const ushort4*)&in[(size_t)(kt + kl + 3) * NTOT + nt + nl];
    *(ushort4*)&sT[nl + 0][kl] = make_ushort4(r0.x, r1.x, r2.x, r3.x);
    *(ushort4*)&sT[nl + 1][kl] = make_ushort4(r0.y, r1.y, r2.y, r3.y);
    *(ushort4*)&sT[nl + 2][kl] = make_ushort4(r0.z, r1.z, r2.z, r3.z);
    *(ushort4*)&sT[nl + 3][kl] = make_ushort4(r0.w, r1.w, r2.w, r3.w);
    __syncthreads();
    #pragma unroll
    for (int pass = 0; pass < 4; ++pass) {
        const int nr = (t >> 4) + pass * 16, ck = (t & 15) * 4;
        *(ushort4*)&out[(size_t)(nt + nr) * CC + kt + ck] = *(const ushort4*)&sT[nr][ck];
    }
}

// ---------------------------------------------------------------------------
// MFMA GEMM:  OUT[oc][n] = sum_k WA[oc][k] * BT[n][k] + bias[oc]
// 128x128 tile, BK=32, 4 waves (2x2), 4x4 16x16x32 fragments per wave.
// OUT_BF16: bf16 [OC][NTOT] via LDS bounce.  else fp32 NCHW (b = n/3136).
// ---------------------------------------------------------------------------
template <int OC, bool OUT_BF16>
__global__ __launch_bounds__(256) void pconv_mfma(const ushort* __restrict__ bt,
                                                  const ushort* __restrict__ wa,
                                                  const float* __restrict__ bias,
                                                  void* __restrict__ outv) {
    __shared__ __align__(16) char smem[OUT_BF16 ? 34816 : 16384];
    ushort (* const sA)[32] = (ushort(*)[32])smem;            // 128x32 weights
    ushort (* const sB)[32] = (ushort(*)[32])(smem + 8192);   // 128x32 inputs

    const int n0  = blockIdx.x * 128;
    const int oc0 = blockIdx.y * 128;
    const int t   = threadIdx.x;
    const int l   = t & 63;
    const int wm  = (t >> 6) >> 1, wn = (t >> 6) & 1;

    f32x4 acc[4][4] = {};

    // staging chunk geometry: chunk c covers LDS bytes [16c,16c+16) = row c>>2, k (c&3)*8
    const int cm0 = t >> 2,        ck0 = (t & 3) * 8;
    const int cm1 = (t + 256) >> 2, ck1 = ((t + 256) & 3) * 8;
    char* const ldsA = smem + (t & 192) * 16;          // wave-uniform base
    char* const ldsB = smem + 8192 + (t & 192) * 16;

    for (int k0 = 0; k0 < CC; k0 += 32) {
        __builtin_amdgcn_global_load_lds(
            (const __attribute__((address_space(1))) void*)(wa + (size_t)(oc0 + cm0) * CC + k0 + ck0),
            (__attribute__((address_space(3))) void*)ldsA, 16, 0, 0);
        __builtin_amdgcn_global_load_lds(
            (const __attribute__((address_space(1))) void*)(wa + (size_t)(oc0 + cm1) * CC + k0 + ck1),
            (__attribute__((address_space(3))) void*)(ldsA + 4096), 16, 0, 0);
        __builtin_amdgcn_global_load_lds(
            (const __attribute__((address_space(1))) void*)(bt + (size_t)(n0 + cm0) * CC + k0 + ck0),
            (__attribute__((address_space(3))) void*)ldsB, 16, 0, 0);
        __builtin_amdgcn_global_load_lds(
            (const __attribute__((address_space(1))) void*)(bt + (size_t)(n0 + cm1) * CC + k0 + ck1),
            (__attribute__((address_space(3))) void*)(ldsB + 4096), 16, 0, 0);
        __syncthreads();
        bf16x8 a[4], b[4];
        #pragma unroll
        for (int i = 0; i < 4; ++i)
            a[i] = *(const bf16x8*)&sA[wm * 64 + i * 16 + (l & 15)][(l >> 4) * 8];
        #pragma unroll
        for (int i = 0; i < 4; ++i)
            b[i] = *(const bf16x8*)&sB[wn * 64 + i * 16 + (l & 15)][(l >> 4) * 8];
        #pragma unroll
        for (int mf = 0; mf < 4; ++mf)
            #pragma unroll
            for (int nf = 0; nf < 4; ++nf)
                acc[mf][nf] = __builtin_amdgcn_mfma_f32_16x16x32_bf16(a[mf], b[nf], acc[mf][nf], 0, 0, 0);
        __syncthreads();
    }

    const int rl = (l >> 4) * 4;   // fragment row base
    const int cl = l & 15;         // fragment col
    if (OUT_BF16) {
        ushort (* const sD)[136] = (ushort(*)[136])smem;
        #pragma unroll
        for (int mf = 0; mf < 4; ++mf) {
            const int row = wm * 64 + mf * 16 + rl;
            #pragma unroll
            for (int nf = 0; nf < 4; ++nf) {
                const int col = wn * 64 + nf * 16 + cl;
                #pragma unroll
                for (int r = 0; r < 4; ++r)
                    sD[row + r][col] = f2b(acc[mf][nf][r] + bias[oc0 + row + r]);
            }
        }
        __syncthreads();
        ushort* outp = (ushort*)outv;
        #pragma unroll
        for (int rr = 0; rr < 8; ++rr) {
            const int r = (t >> 4) + rr * 16;
            *(uint4*)&outp[(size_t)(oc0 + r) * NTOT + n0 + (t & 15) * 8] =
                *(const uint4*)&sD[r][(t & 15) * 8];
        }
    } else {
        float* outp = (float*)outv;
        #pragma unroll
        for (int mf = 0; mf < 4; ++mf) {
            const int row = oc0 + wm * 64 + mf * 16 + rl;
            #pragma unroll
            for (int r = 0; r < 4; ++r) {
                const float bs = bias[row + r];
                #pragma unroll
                for (int nf = 0; nf < 4; ++nf) {
                    const int n = n0 + wn * 64 + nf * 16 + cl;
                    const int b = n / HWP, p = n - b * HWP;
                    outp[((size_t)b * OC + row + r) * HWP + p] = acc[mf][nf][r] + bs;
                }
            }
        }
    }
}

// ---------------------------------------------------------------------------
// Windowed attention, bf16 in [ch][NTOT], bf16 out [c][b][p] (c-major).
// ---------------------------------------------------------------------------
__global__ __launch_bounds__(256) void attn_win(const ushort* __restrict__ qkv,
                                                const float* __restrict__ pos,
                                                ushort* __restrict__ out) {
    __shared__ float sQ[HD][WSQ];
    __shared__ float sK[HD][WSQ];
    __shared__ float sV[HD][WSQ];
    __shared__ float sS[WSQ][WSQ];
    __shared__ float sP[169];

    const int w = blockIdx.x, h = blockIdx.y, b = blockIdx.z;
    const int wr = w >> 3, wc = w & 7;
    const int t = threadIdx.x;
    if (t < 169) sP[t] = pos[t];

    const size_t basen = (size_t)b * HWP;
    for (int e = t; e < HD * WSQ; e += 256) {
        const int d = e / WSQ, p = e - d * WSQ;
        const int pr = p / WSZ, pc = p - pr * WSZ;
        const size_t pix = basen + (wr * WSZ + pr) * HH + wc * WSZ + pc;
        const size_t chq = (size_t)(h * HD + d) * NTOT;
        sQ[d][p] = b2f(qkv[chq + pix]);
        sK[d][p] = b2f(qkv[(size_t)CC * NTOT + chq + pix]);
        sV[d][p] = b2f(qkv[(size_t)2 * CC * NTOT + chq + pix]);
    }
    __syncthreads();

    for (int e = t; e < WSQ * WSQ; e += 256) {
        const int i = e / WSQ, j = e - i * WSQ;
        float s = 0.f;
        #pragma unroll
        for (int d = 0; d < HD; ++d) s += sQ[d][i] * sK[d][j];
        const int pir = i / WSZ, pic = i - pir * WSZ;
        const int pjr = j / WSZ, pjc = j - pjr * WSZ;
        s = s * DKS + sP[(pjr - pir + 6) * 13 + (pjc - pic + 6)];
        const bool m = (wr == 7 && ((pir >= 4) != (pjr >= 4))) ||
                       (wc == 7 && ((pic >= 4) != (pjc >= 4)));
        sS[i][j] = m ? -1e30f : s;
    }
    __syncthreads();

    {   // wave-parallel softmax: 4 lanes per row
        const int r = t >> 2, j0 = t & 3;
        if (r < WSQ) {
            float mx = -1e30f;
            for (int j = j0; j < WSQ; j += 4) mx = fmaxf(mx, sS[r][j]);
            mx = fmaxf(mx, __shfl_xor(mx, 1));
            mx = fmaxf(mx, __shfl_xor(mx, 2));
            float sum = 0.f;
            for (int j = j0; j < WSQ; j += 4) {
                const float e2 = __expf(sS[r][j] - mx);
                sS[r][j] = e2;
                sum += e2;
            }
            sum += __shfl_xor(sum, 1);
            sum += __shfl_xor(sum, 2);
            const float inv = 1.f / sum;
            for (int j = j0; j < WSQ; j += 4) sS[r][j] *= inv;
        }
    }
    __syncthreads();

    for (int e = t; e < HD * WSQ; e += 256) {
        const int d = e / WSQ, p = e - d * WSQ;
        float s = 0.f;
        #pragma unroll 7
        for (int j = 0; j < WSQ; ++j) s += sS[p][j] * sV[d][j];
        const int pr = p / WSZ, pc = p - pr * WSZ;
        out[((size_t)(h * HD + d) * BQ + b) * HWP + (wr * WSZ + pr) * HH + wc * WSZ + pc] = f2b(s);
    }
}

// ---------------------------------------------------------------------------
extern "C" void kernel_launch(void* const* d_in, const int* in_sizes, int n_in,
                              void* d_out, int out_size, void* d_ws, size_t ws_size,
                              hipStream_t stream) {
    const float* x      = (const float*)d_in[0];
    const float* qkv_dw = (const float*)d_in[1];
    const float* qkv_pw = (const float*)d_in[2];
    const float* qkv_pb = (const float*)d_in[3];
    const float* out_dw = (const float*)d_in[4];
    const float* out_pw = (const float*)d_in[5];
    const float* out_pb = (const float*)d_in[6];
    const float* pos    = (const float*)d_in[7];

    ushort* t1   = (ushort*)d_ws;               // [384][NTOT]   (later: attn out)
    ushort* t1t  = t1 + (size_t)CC * NTOT;      // [NTOT][384]   (later: dconv2 out)
    ushort* qkvb = t1t + (size_t)CC * NTOT;     // [1152][NTOT]  (later: t2 transposed)
    ushort* wA1  = qkvb + (size_t)C3 * NTOT;    // [1152][384]
    ushort* wA2  = wA1 + (size_t)C3 * CC;       // [384][384]

    cvt_bf16<<<(C3 * CC + 255) / 256, 256, 0, stream>>>(qkv_pw, wA1, C3 * CC);
    cvt_bf16<<<(CC * CC + 255) / 256, 256, 0, stream>>>(out_pw, wA2, CC * CC);

    roll_dconv<false, false><<<BQ * CC, 256, 0, stream>>>(x, qkv_dw, t1, 3);
    transpose_nk<<<dim3(NTOT / 64, CC / 64), 256, 0, stream>>>(t1, t1t);
    pconv_mfma<C3, true><<<dim3(NTOT / 128, C3 / 128), 256, 0, stream>>>(t1t, wA1, qkv_pb, qkvb);
    attn_win<<<dim3(NWIN, NHEAD, BQ), 256, 0, stream>>>(qkvb, pos, t1);
    roll_dconv<true, true><<<BQ * CC, 256, 0, stream>>>(t1, out_dw, t1t, -3);
    transpose_nk<<<dim3(NTOT / 64, CC / 64), 256, 0, stream>>>(t1t, qkvb);
    pconv_mfma<CC, false><<<dim3(NTOT / 128, CC / 128), 256, 0, stream>>>(qkvb, wA2, out_pb, (float*)d_out);
}

// Round 7
// 440.561 us; speedup vs baseline: 2.8081x; 1.2883x over previous
//
#include <hip/hip_runtime.h>
#include <hip/hip_bf16.h>
#include <cstddef>
#include <cstdint>

#define BQ    16
#define CC    384
#define C3    1152
#define HH    56
#define HWP   3136
#define NTOT  (BQ * HWP)   // 50176
#define NHEAD 12
#define HD    32
#define WSZ   7
#define NWIN  64
#define WSQ   49
#define DKS   0.17677669529663687f

typedef __attribute__((ext_vector_type(8))) short bf16x8;
typedef __attribute__((ext_vector_type(4))) float f32x4;

union U128 { uint4 u; bf16x8 v; ushort us[8]; };

__device__ __forceinline__ ushort f2b(float f) {
    __hip_bfloat16 h = __float2bfloat16(f);
    return *reinterpret_cast<ushort*>(&h);
}
__device__ __forceinline__ float b2f(ushort u) {
    __hip_bfloat16 h;
    *reinterpret_cast<ushort*>(&h) = u;
    return __bfloat162float(h);
}

__global__ void cvt_bf16(const float* __restrict__ in, ushort* __restrict__ out, int n) {
    const int i = blockIdx.x * 256 + threadIdx.x;
    if (i < n) out[i] = f2b(in[i]);
}

// ---------------------------------------------------------------------------
// roll + depthwise 3x3, pixel-major output [n][384].
// BF16IN=false: input fp32 [b][384][56][56] (x).  true: bf16 [n][384] (att).
// Grid (14 bands, 12 cgroups, 16 b); 4 out rows/band, 32 ch/cgroup.
// shiftAdd: +3 (first dconv) or +53 (== -3 mod 56, second dconv).
// ---------------------------------------------------------------------------
template <bool BF16IN>
__global__ __launch_bounds__(256) void dconv_px(const void* __restrict__ inv,
                                                const float* __restrict__ dw,
                                                ushort* __restrict__ out,
                                                int shiftAdd) {
    __shared__ float pl[32][6][57];
    __shared__ float wl[32][9];
    const int band = blockIdx.x, cg = blockIdx.y, b = blockIdx.z;
    const int i0 = band * 4;
    const int t = threadIdx.x;

    for (int idx = t; idx < 32 * 6 * 56; idx += 256) {
        int ch, lr, col;
        if (BF16IN) { ch = idx & 31; const int rem = idx >> 5; lr = rem / 56; col = rem - lr * 56; }
        else        { ch = idx / 336; const int rem = idx - ch * 336; lr = rem / 56; col = rem - lr * 56; }
        const int gi = i0 + lr - 1;
        float v = 0.f;
        if (gi >= 0 && gi < HH) {
            int rr = gi + shiftAdd;  if (rr >= HH) rr -= HH;
            int cc = col + shiftAdd; if (cc >= HH) cc -= HH;
            if (BF16IN) {
                const ushort* src = (const ushort*)inv;
                v = b2f(src[(size_t)(b * HWP + rr * HH + cc) * CC + cg * 32 + ch]);
            } else {
                const float* src = (const float*)inv;
                v = src[((size_t)(b * CC + cg * 32 + ch)) * HWP + rr * HH + cc];
            }
        }
        pl[ch][lr][col] = v;
    }
    // FIX (round 6): 288 entries > 256 threads — must loop, not guard.
    for (int s2 = t; s2 < 288; s2 += 256)
        wl[s2 / 9][s2 % 9] = dw[(cg * 32 + s2 / 9) * 9 + s2 % 9];
    __syncthreads();

    for (int o = t; o < 32 * 4 * 56; o += 256) {
        const int ch = o & 31;
        const int rem = o >> 5;
        const int il = rem / 56, col = rem - il * 56;
        float acc = 0.f;
        #pragma unroll
        for (int di = 0; di < 3; ++di) {
            #pragma unroll
            for (int dj = 0; dj < 3; ++dj) {
                const int jc = col + dj - 1;
                if (jc >= 0 && jc < HH)
                    acc += wl[ch][di * 3 + dj] * pl[ch][il + di][jc];
            }
        }
        out[(size_t)(b * HWP + (i0 + il) * HH + col) * CC + cg * 32 + ch] = f2b(acc);
    }
}

// ---------------------------------------------------------------------------
// MFMA GEMM:  OUT[oc][n] = sum_k WA[oc][k] * BT[n][k] + bias[oc]
// 128x128 tile, BK=32, 4 waves (2x2), 4x4 16x16x32 fragments per wave.
// OUT_BF16: bf16 [n][OC] pixel-major via LDS bounce.  else fp32 NCHW.
// ---------------------------------------------------------------------------
template <int OC, bool OUT_BF16>
__global__ __launch_bounds__(256) void pconv_mfma(const ushort* __restrict__ bt,
                                                  const ushort* __restrict__ wa,
                                                  const float* __restrict__ bias,
                                                  void* __restrict__ outv) {
    __shared__ __align__(16) char smem[OUT_BF16 ? 34816 : 16384];
    ushort (* const sA)[32] = (ushort(*)[32])smem;            // 128x32 weights
    ushort (* const sB)[32] = (ushort(*)[32])(smem + 8192);   // 128x32 inputs

    const int n0  = blockIdx.x * 128;
    const int oc0 = blockIdx.y * 128;
    const int t   = threadIdx.x;
    const int l   = t & 63;
    const int wm  = (t >> 6) >> 1, wn = (t >> 6) & 1;

    f32x4 acc[4][4] = {};

    const int cm0 = t >> 2,        ck0 = (t & 3) * 8;
    const int cm1 = (t + 256) >> 2, ck1 = ((t + 256) & 3) * 8;
    char* const ldsA = smem + (t & 192) * 16;          // wave-uniform base
    char* const ldsB = smem + 8192 + (t & 192) * 16;

    for (int k0 = 0; k0 < CC; k0 += 32) {
        __builtin_amdgcn_global_load_lds(
            (const __attribute__((address_space(1))) void*)(wa + (size_t)(oc0 + cm0) * CC + k0 + ck0),
            (__attribute__((address_space(3))) void*)ldsA, 16, 0, 0);
        __builtin_amdgcn_global_load_lds(
            (const __attribute__((address_space(1))) void*)(wa + (size_t)(oc0 + cm1) * CC + k0 + ck1),
            (__attribute__((address_space(3))) void*)(ldsA + 4096), 16, 0, 0);
        __builtin_amdgcn_global_load_lds(
            (const __attribute__((address_space(1))) void*)(bt + (size_t)(n0 + cm0) * CC + k0 + ck0),
            (__attribute__((address_space(3))) void*)ldsB, 16, 0, 0);
        __builtin_amdgcn_global_load_lds(
            (const __attribute__((address_space(1))) void*)(bt + (size_t)(n0 + cm1) * CC + k0 + ck1),
            (__attribute__((address_space(3))) void*)(ldsB + 4096), 16, 0, 0);
        __syncthreads();
        bf16x8 a[4], bb[4];
        #pragma unroll
        for (int i = 0; i < 4; ++i)
            a[i] = *(const bf16x8*)&sA[wm * 64 + i * 16 + (l & 15)][(l >> 4) * 8];
        #pragma unroll
        for (int i = 0; i < 4; ++i)
            bb[i] = *(const bf16x8*)&sB[wn * 64 + i * 16 + (l & 15)][(l >> 4) * 8];
        #pragma unroll
        for (int mf = 0; mf < 4; ++mf)
            #pragma unroll
            for (int nf = 0; nf < 4; ++nf)
                acc[mf][nf] = __builtin_amdgcn_mfma_f32_16x16x32_bf16(a[mf], bb[nf], acc[mf][nf], 0, 0, 0);
        __syncthreads();
    }

    const int rl = (l >> 4) * 4;   // fragment row base (oc dim)
    const int cl = l & 15;         // fragment col (n dim)
    if (OUT_BF16) {
        ushort (* const sD)[136] = (ushort(*)[136])smem;
        #pragma unroll
        for (int mf = 0; mf < 4; ++mf) {
            const int ocl = wm * 64 + mf * 16 + rl;
            #pragma unroll
            for (int nf = 0; nf < 4; ++nf) {
                const int nl = wn * 64 + nf * 16 + cl;
                ushort4 w4;
                w4.x = f2b(acc[mf][nf][0] + bias[oc0 + ocl + 0]);
                w4.y = f2b(acc[mf][nf][1] + bias[oc0 + ocl + 1]);
                w4.z = f2b(acc[mf][nf][2] + bias[oc0 + ocl + 2]);
                w4.w = f2b(acc[mf][nf][3] + bias[oc0 + ocl + 3]);
                *(ushort4*)&sD[nl][ocl] = w4;
            }
        }
        __syncthreads();
        ushort* outp = (ushort*)outv;
        #pragma unroll
        for (int rr = 0; rr < 8; ++rr) {
            const int r = (t >> 4) + rr * 16;
            const int c8 = (t & 15) * 8;
            *(uint4*)&outp[(size_t)(n0 + r) * C3 + oc0 + c8] = *(const uint4*)&sD[r][c8];
        }
    } else {
        float* outp = (float*)outv;
        #pragma unroll
        for (int mf = 0; mf < 4; ++mf) {
            const int row = oc0 + wm * 64 + mf * 16 + rl;
            #pragma unroll
            for (int r = 0; r < 4; ++r) {
                const float bs = bias[row + r];
                #pragma unroll
                for (int nf = 0; nf < 4; ++nf) {
                    const int n = n0 + wn * 64 + nf * 16 + cl;
                    const int b = n / HWP, p = n - b * HWP;
                    outp[((size_t)b * OC + row + r) * HWP + p] = acc[mf][nf][r] + bs;
                }
            }
        }
    }
}

// ---------------------------------------------------------------------------
// MFMA windowed attention.  qkv [n][1152] bf16 -> att [n][384] bf16.
// One wave per (window, head): S^T = mfma(K,Q) padded 49->64, in-register
// softmax (in-lane 16 + shfl_xor 16/32), P -> LDS bf16, PV = mfma(P, V^T)
// with chunk-XOR-swizzled V tile, O bounced through P tile for uint4 stores.
// Grid (64 windows, 3 head-groups, 16 b), 256 threads = 4 waves (4 heads).
// ---------------------------------------------------------------------------
__global__ __launch_bounds__(256) void attn_mfma(const ushort* __restrict__ qkv,
                                                 const float* __restrict__ pos,
                                                 ushort* __restrict__ out) {
    __shared__ float sPb[169];
    __shared__ __align__(16) ushort sV[4][64 * 40];    // per-wave V [pix][d] swizzled
    __shared__ __align__(16) ushort sPl[4][64 * 72];   // per-wave P, then O bounce

    const int w = blockIdx.x, hg = blockIdx.y, b = blockIdx.z;
    const int wr = w >> 3, wc = w & 7;
    const int t = threadIdx.x, ww = t >> 6, l = t & 63;
    const int h = hg * 4 + ww;
    const int i15 = l & 15, g = l >> 4;
    const int hch = h * HD;
    if (t < 169) sPb[t] = pos[t];
    ushort* const sVw = sV[ww];
    ushort* const sPw = sPl[ww];

    // ---- stage V (rows 49..63 zeroed), chunk-XOR swizzle on d-chunks ----
    #pragma unroll
    for (int pass = 0; pass < 4; ++pass) {
        const int e = l + pass * 64;
        const int pix = e >> 2, c8 = e & 3;
        uint4 v = make_uint4(0, 0, 0, 0);
        if (pix < WSQ) {
            const int n = b * HWP + (wr * WSZ + pix / 7) * HH + wc * WSZ + pix % 7;
            v = *(const uint4*)&qkv[(size_t)n * C3 + 2 * CC + hch + c8 * 8];
        }
        const int cst = c8 ^ ((pix >> 2) & 3);
        *(uint4*)&sVw[pix * 40 + cst * 8] = v;
    }

    // ---- Q (B-frag) and K (A-frag) direct from global, zero-padded ----
    bf16x8 qf[4], kf[4];
    #pragma unroll
    for (int it = 0; it < 4; ++it) {
        const int i = it * 16 + i15;
        U128 uq, uk;
        uq.u = make_uint4(0, 0, 0, 0);
        uk.u = make_uint4(0, 0, 0, 0);
        if (i < WSQ) {
            const int n = b * HWP + (wr * WSZ + i / 7) * HH + wc * WSZ + i % 7;
            uq.u = *(const uint4*)&qkv[(size_t)n * C3 + hch + g * 8];
            uk.u = *(const uint4*)&qkv[(size_t)n * C3 + CC + hch + g * 8];
        }
        qf[it] = uq.v;
        kf[it] = uk.v;
    }

    // ---- S^T = K·Q^T : D[j][i], lane holds i = it*16+i15, j = jt*16+4g+r ----
    f32x4 sS[4][4] = {};
    #pragma unroll
    for (int jt = 0; jt < 4; ++jt)
        #pragma unroll
        for (int it = 0; it < 4; ++it)
            sS[jt][it] = __builtin_amdgcn_mfma_f32_16x16x32_bf16(kf[jt], qf[it], sS[jt][it], 0, 0, 0);

    __syncthreads();   // sPb ready (block-wide); per-wave LDS needs no barrier

    // ---- fold scale + rel-pos bias + shift mask ----
    #pragma unroll
    for (int jt = 0; jt < 4; ++jt) {
        #pragma unroll
        for (int r = 0; r < 4; ++r) {
            const int j = jt * 16 + 4 * g + r;
            const bool jv = j < WSQ;
            const int pjr = j / 7, pjc = j % 7;
            #pragma unroll
            for (int it = 0; it < 4; ++it) {
                const int i = it * 16 + i15;
                float s = -1e30f;
                if ((i < WSQ) && jv) {
                    const int pir = i / 7, pic = i % 7;
                    s = sS[jt][it][r] * DKS + sPb[(pjr - pir + 6) * 13 + (pjc - pic + 6)];
                    if ((wr == 7 && ((pir >= 4) != (pjr >= 4))) ||
                        (wc == 7 && ((pic >= 4) != (pjc >= 4)))) s = -1e30f;
                }
                sS[jt][it][r] = s;
            }
        }
    }

    // ---- softmax over j per column i: 16 in-lane + lanes l^16, l^32 ----
    #pragma unroll
    for (int it = 0; it < 4; ++it) {
        float m = -1e30f;
        #pragma unroll
        for (int jt = 0; jt < 4; ++jt)
            #pragma unroll
            for (int r = 0; r < 4; ++r) m = fmaxf(m, sS[jt][it][r]);
        m = fmaxf(m, __shfl_xor(m, 16));
        m = fmaxf(m, __shfl_xor(m, 32));
        float sum = 0.f;
        #pragma unroll
        for (int jt = 0; jt < 4; ++jt)
            #pragma unroll
            for (int r = 0; r < 4; ++r) {
                const float e2 = __expf(sS[jt][it][r] - m);
                sS[jt][it][r] = e2;
                sum += e2;
            }
        sum += __shfl_xor(sum, 16);
        sum += __shfl_xor(sum, 32);
        const float inv = 1.f / sum;
        #pragma unroll
        for (int jt = 0; jt < 4; ++jt)
            #pragma unroll
            for (int r = 0; r < 4; ++r) sS[jt][it][r] *= inv;
    }

    // ---- pack P to bf16, write P_lds[i][j] (pad 72) ----
    #pragma unroll
    for (int it = 0; it < 4; ++it) {
        const int i = it * 16 + i15;
        #pragma unroll
        for (int jt = 0; jt < 4; ++jt) {
            const uint lo = (uint)f2b(sS[jt][it][0]) | ((uint)f2b(sS[jt][it][1]) << 16);
            const uint hi = (uint)f2b(sS[jt][it][2]) | ((uint)f2b(sS[jt][it][3]) << 16);
            *(uint2*)&sPw[i * 72 + jt * 16 + 4 * g] = make_uint2(lo, hi);
        }
    }

    // ---- PV: O[i][d] = sum_j P[i][j] V[j][d] ----
    f32x4 oacc[4][2] = {};
    #pragma unroll
    for (int kt = 0; kt < 2; ++kt) {
        bf16x8 pa[4];
        #pragma unroll
        for (int mt = 0; mt < 4; ++mt)
            pa[mt] = *(const bf16x8*)&sPw[(mt * 16 + i15) * 72 + kt * 32 + g * 8];
        bf16x8 bv[2];
        #pragma unroll
        for (int nt = 0; nt < 2; ++nt) {
            U128 u;
            #pragma unroll
            for (int s = 0; s < 8; ++s) {
                const int j = kt * 32 + 8 * g + s;
                const int d = nt * 16 + i15;
                const int cp = (d >> 3) ^ ((j >> 2) & 3);
                u.us[s] = sVw[j * 40 + cp * 8 + (d & 7)];
            }
            bv[nt] = u.v;
        }
        #pragma unroll
        for (int mt = 0; mt < 4; ++mt)
            #pragma unroll
            for (int nt = 0; nt < 2; ++nt)
                oacc[mt][nt] = __builtin_amdgcn_mfma_f32_16x16x32_bf16(pa[mt], bv[nt], oacc[mt][nt], 0, 0, 0);
    }

    // ---- O bounce through sPw (pad 40, chunk-XOR by (i>>2)&3) ----
    #pragma unroll
    for (int mt = 0; mt < 4; ++mt)
        #pragma unroll
        for (int nt = 0; nt < 2; ++nt)
            #pragma unroll
            for (int r = 0; r < 4; ++r) {
                const int i = mt * 16 + 4 * g + r;
                const int d = nt * 16 + i15;
                const int cp = (d >> 3) ^ ((i >> 2) & 3);
                sPw[i * 40 + cp * 8 + (d & 7)] = f2b(oacc[mt][nt][r]);
            }

    // ---- coalesced readout ----
    #pragma unroll
    for (int pass = 0; pass < 4; ++pass) {
        const int e = l + pass * 64;
        const int pix = e >> 2, c8 = e & 3;
        if (pix < WSQ) {
            const int n = b * HWP + (wr * WSZ + pix / 7) * HH + wc * WSZ + pix % 7;
            const int cp = c8 ^ ((pix >> 2) & 3);
            *(uint4*)&out[(size_t)n * CC + hch + c8 * 8] = *(const uint4*)&sPw[pix * 40 + cp * 8];
        }
    }
}

// ---------------------------------------------------------------------------
extern "C" void kernel_launch(void* const* d_in, const int* in_sizes, int n_in,
                              void* d_out, int out_size, void* d_ws, size_t ws_size,
                              hipStream_t stream) {
    const float* x      = (const float*)d_in[0];
    const float* qkv_dw = (const float*)d_in[1];
    const float* qkv_pw = (const float*)d_in[2];
    const float* qkv_pb = (const float*)d_in[3];
    const float* out_dw = (const float*)d_in[4];
    const float* out_pw = (const float*)d_in[5];
    const float* out_pb = (const float*)d_in[6];
    const float* pos    = (const float*)d_in[7];

    // ws: A [NTOT][384] | B [NTOT][1152] | wA1 [1152][384] | wA2 [384][384]
    ushort* A   = (ushort*)d_ws;
    ushort* B   = A + (size_t)NTOT * CC;
    ushort* wA1 = B + (size_t)NTOT * C3;
    ushort* wA2 = wA1 + (size_t)C3 * CC;

    cvt_bf16<<<(C3 * CC + 255) / 256, 256, 0, stream>>>(qkv_pw, wA1, C3 * CC);
    cvt_bf16<<<(CC * CC + 255) / 256, 256, 0, stream>>>(out_pw, wA2, CC * CC);

    // 1) roll(-3) + depthwise -> A [n][384] bf16
    dconv_px<false><<<dim3(14, 12, BQ), 256, 0, stream>>>(x, qkv_dw, A, 3);
    // 2) pointwise 384->1152 -> B [n][1152] bf16
    pconv_mfma<C3, true><<<dim3(NTOT / 128, C3 / 128), 256, 0, stream>>>(A, wA1, qkv_pb, B);
    // 3) windowed attention -> A [n][384] bf16
    attn_mfma<<<dim3(NWIN, NHEAD / 4, BQ), 256, 0, stream>>>(B, pos, A);
    // 4) roll(+3) + depthwise -> B (reused) [n][384] bf16
    dconv_px<true><<<dim3(14, 12, BQ), 256, 0, stream>>>(A, out_dw, B, 53);
    // 5) pointwise 384->384 -> d_out fp32 NCHW
    pconv_mfma<CC, false><<<dim3(NTOT / 128, CC / 128), 256, 0, stream>>>(B, wA2, out_pb, (float*)d_out);
}

// Round 8
// 308.845 us; speedup vs baseline: 4.0057x; 1.4265x over previous
//
#include <hip/hip_runtime.h>
#include <hip/hip_bf16.h>
#include <cstddef>
#include <cstdint>

#define BQ    16
#define CC    384
#define C3    1152
#define HH    56
#define HWP   3136
#define NTOT  (BQ * HWP)   // 50176
#define NHEAD 12
#define HD    32
#define WSZ   7
#define NWIN  64
#define WSQ   49
#define DKS   0.17677669529663687f

typedef __attribute__((ext_vector_type(8))) short bf16x8;
typedef __attribute__((ext_vector_type(4))) float f32x4;

union U128 { uint4 u; bf16x8 v; ushort us[8]; };

__device__ __forceinline__ ushort f2b(float f) {
    __hip_bfloat16 h = __float2bfloat16(f);
    return *reinterpret_cast<ushort*>(&h);
}
__device__ __forceinline__ float b2f(ushort u) {
    __hip_bfloat16 h;
    *reinterpret_cast<ushort*>(&h) = u;
    return __bfloat162float(h);
}

__global__ void cvt_bf16(const float* __restrict__ in, ushort* __restrict__ out, int n) {
    const int i = blockIdx.x * 256 + threadIdx.x;
    if (i < n) out[i] = f2b(in[i]);
}

// ---------------------------------------------------------------------------
// roll + depthwise 3x3, pixel-major output [n][384].
// LDS pl[6 rows][32 ch][57 cols] (col 56 = zero sentinel): bank = 25*ch+col
// mod 32 -> conflict-free compute reads (25 coprime 32).  Weights in regs.
// 4-col register blocking: 18 LDS reads / 4 outputs.
// Grid (14 bands, 12 cgroups, 16 b); 4 out rows/band, 32 ch/cgroup.
// shiftAdd: +3 (first dconv) or +53 (== -3 mod 56, second dconv).
// ---------------------------------------------------------------------------
template <bool BF16IN>
__global__ __launch_bounds__(256) void dconv_px(const void* __restrict__ inv,
                                                const float* __restrict__ dw,
                                                ushort* __restrict__ out,
                                                int shiftAdd) {
    __shared__ float pl[6][32][57];
    const int band = blockIdx.x, cg = blockIdx.y, b = blockIdx.z;
    const int i0 = band * 4;
    const int t = threadIdx.x;
    const int ch = t & 31;

    // per-thread weights (thread owns channel ch of this cgroup)
    float wreg[9];
    #pragma unroll
    for (int k = 0; k < 9; ++k) wreg[k] = dw[(cg * 32 + ch) * 9 + k];

    // zero sentinel column 56
    if (t < 192) pl[t / 32][t % 32][56] = 0.f;

    if (BF16IN) {
        // input bf16 [n][384]: uint4 = 8 ch per load; lanes: chunk fastest.
        const ushort* src = (const ushort*)inv;
        for (int e = t; e < 6 * 4 * 56; e += 256) {
            const int c8 = e & 3;
            const int rem = e >> 2;
            const int col = rem % 56, lr = rem / 56;
            const int gi = i0 + lr - 1;
            U128 u;
            u.u = make_uint4(0, 0, 0, 0);
            if (gi >= 0 && gi < HH) {
                int rr = gi + shiftAdd;  if (rr >= HH) rr -= HH;
                int cc = col + shiftAdd; if (cc >= HH) cc -= HH;
                u.u = *(const uint4*)&src[(size_t)(b * HWP + rr * HH + cc) * CC + cg * 32 + c8 * 8];
            }
            #pragma unroll
            for (int k = 0; k < 8; ++k) pl[lr][c8 * 8 + k][col] = b2f(u.us[k]);
        }
    } else {
        // input fp32 [b][384][56][56]: scalar loads, col fastest (coalesced).
        const float* src = (const float*)inv;
        for (int e = t; e < 6 * 32 * 56; e += 256) {
            const int col = e % 56;
            const int q = e / 56;
            const int lc = q & 31, lr = q >> 5;
            const int gi = i0 + lr - 1;
            float v = 0.f;
            if (gi >= 0 && gi < HH) {
                int rr = gi + shiftAdd;  if (rr >= HH) rr -= HH;
                int cc = col + shiftAdd; if (cc >= HH) cc -= HH;
                v = src[((size_t)(b * CC + cg * 32 + lc)) * HWP + rr * HH + cc];
            }
            pl[lr][lc][col] = v;
        }
    }
    __syncthreads();

    // compute: 56 units = 4 rows x 14 colblocks; 8 units per pass (t>>5).
    const int u = t >> 5;
    #pragma unroll
    for (int iter = 0; iter < 7; ++iter) {
        const int unit = iter * 8 + u;
        const int row  = unit / 14;
        const int colb = unit - row * 14;
        const int c0 = colb * 4;
        float acc[4] = {0.f, 0.f, 0.f, 0.f};
        #pragma unroll
        for (int di = 0; di < 3; ++di) {
            const float* rp = &pl[row + di][ch][0];
            float v[6];
            #pragma unroll
            for (int k = 0; k < 6; ++k) {
                int c = c0 - 1 + k;
                c = (c < 0 || c > 55) ? 56 : c;   // sentinel = 0
                v[k] = rp[c];
            }
            #pragma unroll
            for (int cc2 = 0; cc2 < 4; ++cc2) {
                acc[cc2] += wreg[di * 3 + 0] * v[cc2];
                acc[cc2] += wreg[di * 3 + 1] * v[cc2 + 1];
                acc[cc2] += wreg[di * 3 + 2] * v[cc2 + 2];
            }
        }
        const int orow = i0 + row;
        #pragma unroll
        for (int cc2 = 0; cc2 < 4; ++cc2)
            out[(size_t)(b * HWP + orow * HH + c0 + cc2) * CC + cg * 32 + ch] = f2b(acc[cc2]);
    }
}

// ---------------------------------------------------------------------------
// MFMA GEMM:  OUT[oc][n] = sum_k WA[oc][k] * BT[n][k] + bias[oc]
// 128x128 tile, BK=32, 4 waves (2x2), 4x4 16x16x32 fragments per wave.
// OUT_BF16: bf16 [n][OC] pixel-major via LDS bounce.  else fp32 NCHW.
// ---------------------------------------------------------------------------
template <int OC, bool OUT_BF16>
__global__ __launch_bounds__(256) void pconv_mfma(const ushort* __restrict__ bt,
                                                  const ushort* __restrict__ wa,
                                                  const float* __restrict__ bias,
                                                  void* __restrict__ outv) {
    __shared__ __align__(16) char smem[OUT_BF16 ? 34816 : 16384];
    ushort (* const sA)[32] = (ushort(*)[32])smem;            // 128x32 weights
    ushort (* const sB)[32] = (ushort(*)[32])(smem + 8192);   // 128x32 inputs

    const int n0  = blockIdx.x * 128;
    const int oc0 = blockIdx.y * 128;
    const int t   = threadIdx.x;
    const int l   = t & 63;
    const int wm  = (t >> 6) >> 1, wn = (t >> 6) & 1;

    f32x4 acc[4][4] = {};

    const int cm0 = t >> 2,        ck0 = (t & 3) * 8;
    const int cm1 = (t + 256) >> 2, ck1 = ((t + 256) & 3) * 8;
    char* const ldsA = smem + (t & 192) * 16;          // wave-uniform base
    char* const ldsB = smem + 8192 + (t & 192) * 16;

    for (int k0 = 0; k0 < CC; k0 += 32) {
        __builtin_amdgcn_global_load_lds(
            (const __attribute__((address_space(1))) void*)(wa + (size_t)(oc0 + cm0) * CC + k0 + ck0),
            (__attribute__((address_space(3))) void*)ldsA, 16, 0, 0);
        __builtin_amdgcn_global_load_lds(
            (const __attribute__((address_space(1))) void*)(wa + (size_t)(oc0 + cm1) * CC + k0 + ck1),
            (__attribute__((address_space(3))) void*)(ldsA + 4096), 16, 0, 0);
        __builtin_amdgcn_global_load_lds(
            (const __attribute__((address_space(1))) void*)(bt + (size_t)(n0 + cm0) * CC + k0 + ck0),
            (__attribute__((address_space(3))) void*)ldsB, 16, 0, 0);
        __builtin_amdgcn_global_load_lds(
            (const __attribute__((address_space(1))) void*)(bt + (size_t)(n0 + cm1) * CC + k0 + ck1),
            (__attribute__((address_space(3))) void*)(ldsB + 4096), 16, 0, 0);
        __syncthreads();
        bf16x8 a[4], bb[4];
        #pragma unroll
        for (int i = 0; i < 4; ++i)
            a[i] = *(const bf16x8*)&sA[wm * 64 + i * 16 + (l & 15)][(l >> 4) * 8];
        #pragma unroll
        for (int i = 0; i < 4; ++i)
            bb[i] = *(const bf16x8*)&sB[wn * 64 + i * 16 + (l & 15)][(l >> 4) * 8];
        #pragma unroll
        for (int mf = 0; mf < 4; ++mf)
            #pragma unroll
            for (int nf = 0; nf < 4; ++nf)
                acc[mf][nf] = __builtin_amdgcn_mfma_f32_16x16x32_bf16(a[mf], bb[nf], acc[mf][nf], 0, 0, 0);
        __syncthreads();
    }

    const int rl = (l >> 4) * 4;   // fragment row base (oc dim)
    const int cl = l & 15;         // fragment col (n dim)
    if (OUT_BF16) {
        ushort (* const sD)[136] = (ushort(*)[136])smem;
        #pragma unroll
        for (int mf = 0; mf < 4; ++mf) {
            const int ocl = wm * 64 + mf * 16 + rl;
            #pragma unroll
            for (int nf = 0; nf < 4; ++nf) {
                const int nl = wn * 64 + nf * 16 + cl;
                ushort4 w4;
                w4.x = f2b(acc[mf][nf][0] + bias[oc0 + ocl + 0]);
                w4.y = f2b(acc[mf][nf][1] + bias[oc0 + ocl + 1]);
                w4.z = f2b(acc[mf][nf][2] + bias[oc0 + ocl + 2]);
                w4.w = f2b(acc[mf][nf][3] + bias[oc0 + ocl + 3]);
                *(ushort4*)&sD[nl][ocl] = w4;
            }
        }
        __syncthreads();
        ushort* outp = (ushort*)outv;
        #pragma unroll
        for (int rr = 0; rr < 8; ++rr) {
            const int r = (t >> 4) + rr * 16;
            const int c8 = (t & 15) * 8;
            *(uint4*)&outp[(size_t)(n0 + r) * C3 + oc0 + c8] = *(const uint4*)&sD[r][c8];
        }
    } else {
        float* outp = (float*)outv;
        #pragma unroll
        for (int mf = 0; mf < 4; ++mf) {
            const int row = oc0 + wm * 64 + mf * 16 + rl;
            #pragma unroll
            for (int r = 0; r < 4; ++r) {
                const float bs = bias[row + r];
                #pragma unroll
                for (int nf = 0; nf < 4; ++nf) {
                    const int n = n0 + wn * 64 + nf * 16 + cl;
                    const int b = n / HWP, p = n - b * HWP;
                    outp[((size_t)b * OC + row + r) * HWP + p] = acc[mf][nf][r] + bs;
                }
            }
        }
    }
}

// ---------------------------------------------------------------------------
// MFMA windowed attention.  qkv [n][1152] bf16 -> att [n][384] bf16.
// One wave per (window, head): S^T = mfma(K,Q) padded 49->64, in-register
// softmax (in-lane 16 + shfl_xor 16/32), P -> LDS bf16, PV = mfma(P, V^T)
// with chunk-XOR-swizzled V tile, O bounced through P tile for uint4 stores.
// Grid (64 windows, 3 head-groups, 16 b), 256 threads = 4 waves (4 heads).
// ---------------------------------------------------------------------------
__global__ __launch_bounds__(256) void attn_mfma(const ushort* __restrict__ qkv,
                                                 const float* __restrict__ pos,
                                                 ushort* __restrict__ out) {
    __shared__ float sPb[169];
    __shared__ __align__(16) ushort sV[4][64 * 40];    // per-wave V [pix][d] swizzled
    __shared__ __align__(16) ushort sPl[4][64 * 72];   // per-wave P, then O bounce

    const int w = blockIdx.x, hg = blockIdx.y, b = blockIdx.z;
    const int wr = w >> 3, wc = w & 7;
    const int t = threadIdx.x, ww = t >> 6, l = t & 63;
    const int h = hg * 4 + ww;
    const int i15 = l & 15, g = l >> 4;
    const int hch = h * HD;
    if (t < 169) sPb[t] = pos[t];
    ushort* const sVw = sV[ww];
    ushort* const sPw = sPl[ww];

    // ---- stage V (rows 49..63 zeroed), chunk-XOR swizzle on d-chunks ----
    #pragma unroll
    for (int pass = 0; pass < 4; ++pass) {
        const int e = l + pass * 64;
        const int pix = e >> 2, c8 = e & 3;
        uint4 v = make_uint4(0, 0, 0, 0);
        if (pix < WSQ) {
            const int n = b * HWP + (wr * WSZ + pix / 7) * HH + wc * WSZ + pix % 7;
            v = *(const uint4*)&qkv[(size_t)n * C3 + 2 * CC + hch + c8 * 8];
        }
        const int cst = c8 ^ ((pix >> 2) & 3);
        *(uint4*)&sVw[pix * 40 + cst * 8] = v;
    }

    // ---- Q (B-frag) and K (A-frag) direct from global, zero-padded ----
    bf16x8 qf[4], kf[4];
    #pragma unroll
    for (int it = 0; it < 4; ++it) {
        const int i = it * 16 + i15;
        U128 uq, uk;
        uq.u = make_uint4(0, 0, 0, 0);
        uk.u = make_uint4(0, 0, 0, 0);
        if (i < WSQ) {
            const int n = b * HWP + (wr * WSZ + i / 7) * HH + wc * WSZ + i % 7;
            uq.u = *(const uint4*)&qkv[(size_t)n * C3 + hch + g * 8];
            uk.u = *(const uint4*)&qkv[(size_t)n * C3 + CC + hch + g * 8];
        }
        qf[it] = uq.v;
        kf[it] = uk.v;
    }

    // ---- S^T = K·Q^T : D[j][i], lane holds i = it*16+i15, j = jt*16+4g+r ----
    f32x4 sS[4][4] = {};
    #pragma unroll
    for (int jt = 0; jt < 4; ++jt)
        #pragma unroll
        for (int it = 0; it < 4; ++it)
            sS[jt][it] = __builtin_amdgcn_mfma_f32_16x16x32_bf16(kf[jt], qf[it], sS[jt][it], 0, 0, 0);

    __syncthreads();   // sPb ready (block-wide); per-wave LDS needs no barrier

    // ---- fold scale + rel-pos bias + shift mask ----
    #pragma unroll
    for (int jt = 0; jt < 4; ++jt) {
        #pragma unroll
        for (int r = 0; r < 4; ++r) {
            const int j = jt * 16 + 4 * g + r;
            const bool jv = j < WSQ;
            const int pjr = j / 7, pjc = j % 7;
            #pragma unroll
            for (int it = 0; it < 4; ++it) {
                const int i = it * 16 + i15;
                float s = -1e30f;
                if ((i < WSQ) && jv) {
                    const int pir = i / 7, pic = i % 7;
                    s = sS[jt][it][r] * DKS + sPb[(pjr - pir + 6) * 13 + (pjc - pic + 6)];
                    if ((wr == 7 && ((pir >= 4) != (pjr >= 4))) ||
                        (wc == 7 && ((pic >= 4) != (pjc >= 4)))) s = -1e30f;
                }
                sS[jt][it][r] = s;
            }
        }
    }

    // ---- softmax over j per column i: 16 in-lane + lanes l^16, l^32 ----
    #pragma unroll
    for (int it = 0; it < 4; ++it) {
        float m = -1e30f;
        #pragma unroll
        for (int jt = 0; jt < 4; ++jt)
            #pragma unroll
            for (int r = 0; r < 4; ++r) m = fmaxf(m, sS[jt][it][r]);
        m = fmaxf(m, __shfl_xor(m, 16));
        m = fmaxf(m, __shfl_xor(m, 32));
        float sum = 0.f;
        #pragma unroll
        for (int jt = 0; jt < 4; ++jt)
            #pragma unroll
            for (int r = 0; r < 4; ++r) {
                const float e2 = __expf(sS[jt][it][r] - m);
                sS[jt][it][r] = e2;
                sum += e2;
            }
        sum += __shfl_xor(sum, 16);
        sum += __shfl_xor(sum, 32);
        const float inv = 1.f / sum;
        #pragma unroll
        for (int jt = 0; jt < 4; ++jt)
            #pragma unroll
            for (int r = 0; r < 4; ++r) sS[jt][it][r] *= inv;
    }

    // ---- pack P to bf16, write P_lds[i][j] (pad 72) ----
    #pragma unroll
    for (int it = 0; it < 4; ++it) {
        const int i = it * 16 + i15;
        #pragma unroll
        for (int jt = 0; jt < 4; ++jt) {
            const uint lo = (uint)f2b(sS[jt][it][0]) | ((uint)f2b(sS[jt][it][1]) << 16);
            const uint hi = (uint)f2b(sS[jt][it][2]) | ((uint)f2b(sS[jt][it][3]) << 16);
            *(uint2*)&sPw[i * 72 + jt * 16 + 4 * g] = make_uint2(lo, hi);
        }
    }

    // ---- PV: O[i][d] = sum_j P[i][j] V[j][d] ----
    f32x4 oacc[4][2] = {};
    #pragma unroll
    for (int kt = 0; kt < 2; ++kt) {
        bf16x8 pa[4];
        #pragma unroll
        for (int mt = 0; mt < 4; ++mt)
            pa[mt] = *(const bf16x8*)&sPw[(mt * 16 + i15) * 72 + kt * 32 + g * 8];
        bf16x8 bv[2];
        #pragma unroll
        for (int nt = 0; nt < 2; ++nt) {
            U128 u;
            #pragma unroll
            for (int s = 0; s < 8; ++s) {
                const int j = kt * 32 + 8 * g + s;
                const int d = nt * 16 + i15;
                const int cp = (d >> 3) ^ ((j >> 2) & 3);
                u.us[s] = sVw[j * 40 + cp * 8 + (d & 7)];
            }
            bv[nt] = u.v;
        }
        #pragma unroll
        for (int mt = 0; mt < 4; ++mt)
            #pragma unroll
            for (int nt = 0; nt < 2; ++nt)
                oacc[mt][nt] = __builtin_amdgcn_mfma_f32_16x16x32_bf16(pa[mt], bv[nt], oacc[mt][nt], 0, 0, 0);
    }

    // ---- O bounce through sPw (pad 40, chunk-XOR by (i>>2)&3) ----
    #pragma unroll
    for (int mt = 0; mt < 4; ++mt)
        #pragma unroll
        for (int nt = 0; nt < 2; ++nt)
            #pragma unroll
            for (int r = 0; r < 4; ++r) {
                const int i = mt * 16 + 4 * g + r;
                const int d = nt * 16 + i15;
                const int cp = (d >> 3) ^ ((i >> 2) & 3);
                sPw[i * 40 + cp * 8 + (d & 7)] = f2b(oacc[mt][nt][r]);
            }

    // ---- coalesced readout ----
    #pragma unroll
    for (int pass = 0; pass < 4; ++pass) {
        const int e = l + pass * 64;
        const int pix = e >> 2, c8 = e & 3;
        if (pix < WSQ) {
            const int n = b * HWP + (wr * WSZ + pix / 7) * HH + wc * WSZ + pix % 7;
            const int cp = c8 ^ ((pix >> 2) & 3);
            *(uint4*)&out[(size_t)n * CC + hch + c8 * 8] = *(const uint4*)&sPw[pix * 40 + cp * 8];
        }
    }
}

// ---------------------------------------------------------------------------
extern "C" void kernel_launch(void* const* d_in, const int* in_sizes, int n_in,
                              void* d_out, int out_size, void* d_ws, size_t ws_size,
                              hipStream_t stream) {
    const float* x      = (const float*)d_in[0];
    const float* qkv_dw = (const float*)d_in[1];
    const float* qkv_pw = (const float*)d_in[2];
    const float* qkv_pb = (const float*)d_in[3];
    const float* out_dw = (const float*)d_in[4];
    const float* out_pw = (const float*)d_in[5];
    const float* out_pb = (const float*)d_in[6];
    const float* pos    = (const float*)d_in[7];

    // ws: A [NTOT][384] | B [NTOT][1152] | wA1 [1152][384] | wA2 [384][384]
    ushort* A   = (ushort*)d_ws;
    ushort* B   = A + (size_t)NTOT * CC;
    ushort* wA1 = B + (size_t)NTOT * C3;
    ushort* wA2 = wA1 + (size_t)C3 * CC;

    cvt_bf16<<<(C3 * CC + 255) / 256, 256, 0, stream>>>(qkv_pw, wA1, C3 * CC);
    cvt_bf16<<<(CC * CC + 255) / 256, 256, 0, stream>>>(out_pw, wA2, CC * CC);

    // 1) roll(-3) + depthwise -> A [n][384] bf16
    dconv_px<false><<<dim3(14, 12, BQ), 256, 0, stream>>>(x, qkv_dw, A, 3);
    // 2) pointwise 384->1152 -> B [n][1152] bf16
    pconv_mfma<C3, true><<<dim3(NTOT / 128, C3 / 128), 256, 0, stream>>>(A, wA1, qkv_pb, B);
    // 3) windowed attention -> A [n][384] bf16
    attn_mfma<<<dim3(NWIN, NHEAD / 4, BQ), 256, 0, stream>>>(B, pos, A);
    // 4) roll(+3) + depthwise -> B (reused) [n][384] bf16
    dconv_px<true><<<dim3(14, 12, BQ), 256, 0, stream>>>(A, out_dw, B, 53);
    // 5) pointwise 384->384 -> d_out fp32 NCHW
    pconv_mfma<CC, false><<<dim3(NTOT / 128, CC / 128), 256, 0, stream>>>(B, wA2, out_pb, (float*)d_out);
}

// Round 9
// 284.866 us; speedup vs baseline: 4.3429x; 1.0842x over previous
//
#include <hip/hip_runtime.h>
#include <hip/hip_bf16.h>
#include <cstddef>
#include <cstdint>

#define BQ    16
#define CC    384
#define C3    1152
#define HH    56
#define HWP   3136
#define NTOT  (BQ * HWP)   // 50176
#define NHEAD 12
#define HD    32
#define WSZ   7
#define NWIN  64
#define WSQ   49
#define DKS   0.17677669529663687f

typedef __attribute__((ext_vector_type(8))) short bf16x8;
typedef __attribute__((ext_vector_type(4))) float f32x4;

union U128 { uint4 u; bf16x8 v; ushort us[8]; };

__device__ __forceinline__ ushort f2b(float f) {
    __hip_bfloat16 h = __float2bfloat16(f);
    return *reinterpret_cast<ushort*>(&h);
}
__device__ __forceinline__ float b2f(ushort u) {
    __hip_bfloat16 h;
    *reinterpret_cast<ushort*>(&h) = u;
    return __bfloat162float(h);
}

__global__ void cvt_bf16(const float* __restrict__ in, ushort* __restrict__ out, int n) {
    const int i = blockIdx.x * 256 + threadIdx.x;
    if (i < n) out[i] = f2b(in[i]);
}

// ---------------------------------------------------------------------------
// roll + depthwise 3x3, pixel-major output [n][384].
// LDS band in BF16: pl[6 rows][32 ch][57 cols] (col 56 = zero sentinel).
// 21.9 KB -> 7 blocks/CU (round-8's fp32 44 KB capped at 3 -> 29% occupancy).
// Stride 57 ushorts keeps the odd-stride low-conflict property (r8: 387K).
// Staging threads own fixed coords (no per-iter div/mod).
// Grid (14 bands, 12 cgroups, 16 b); shiftAdd: +3 or +53 (== -3 mod 56).
// ---------------------------------------------------------------------------
template <bool BF16IN>
__global__ __launch_bounds__(256) void dconv_px(const void* __restrict__ inv,
                                                const float* __restrict__ dw,
                                                ushort* __restrict__ out,
                                                int shiftAdd) {
    __shared__ ushort pl[6][32][57];
    const int band = blockIdx.x, cg = blockIdx.y, b = blockIdx.z;
    const int i0 = band * 4;
    const int t = threadIdx.x;
    const int ch = t & 31;

    // per-thread weights (thread owns channel ch of this cgroup)
    float wreg[9];
    #pragma unroll
    for (int k = 0; k < 9; ++k) wreg[k] = dw[(cg * 32 + ch) * 9 + k];

    // zero sentinel column 56 (6*32 entries)
    if (t < 192) pl[t >> 5][t & 31][56] = 0;

    if (BF16IN) {
        // input bf16 [n][384]: thread owns (c8 = t&3, col = t>>2); walks 6 rows.
        const ushort* src = (const ushort*)inv;
        const int c8 = t & 3, col = t >> 2;
        if (col < 56) {
            int cc = col + shiftAdd; if (cc >= HH) cc -= HH;
            #pragma unroll
            for (int lr = 0; lr < 6; ++lr) {
                const int gi = i0 + lr - 1;
                U128 u; u.u = make_uint4(0, 0, 0, 0);
                if (gi >= 0 && gi < HH) {
                    int rr = gi + shiftAdd; if (rr >= HH) rr -= HH;
                    u.u = *(const uint4*)&src[(size_t)(b * HWP + rr * HH + cc) * CC + cg * 32 + c8 * 8];
                }
                #pragma unroll
                for (int k = 0; k < 8; ++k) pl[lr][c8 * 8 + k][col] = u.us[k];
            }
        }
    } else {
        // input fp32 [b][384][56][56]: thread owns (col = t&63, q0 = t>>6);
        // q = q0 + 4p walks (lc = q&31, lr = q>>5) over 192 (ch,row) pairs.
        const float* src = (const float*)inv;
        const int col = t & 63, q0 = t >> 6;
        if (col < 56) {
            int cc = col + shiftAdd; if (cc >= HH) cc -= HH;
            #pragma unroll 8
            for (int p = 0; p < 48; ++p) {
                const int q = q0 + p * 4;
                const int lc = q & 31, lr = q >> 5;
                const int gi = i0 + lr - 1;
                ushort v = 0;
                if (gi >= 0 && gi < HH) {
                    int rr = gi + shiftAdd; if (rr >= HH) rr -= HH;
                    v = f2b(src[((size_t)(b * CC + cg * 32 + lc)) * HWP + rr * HH + cc]);
                }
                pl[lr][lc][col] = v;
            }
        }
    }
    __syncthreads();

    // compute: 56 units = 14 colblocks x 4 rows; unit = iter*8 + (t>>5);
    // colb = unit>>2, row = unit&3 (pow-2 decode, no div by 14).
    const int u = t >> 5;
    #pragma unroll
    for (int iter = 0; iter < 7; ++iter) {
        const int unit = iter * 8 + u;
        const int colb = unit >> 2;
        const int row  = unit & 3;
        const int c0 = colb * 4;
        float acc[4] = {0.f, 0.f, 0.f, 0.f};
        #pragma unroll
        for (int di = 0; di < 3; ++di) {
            const ushort* rp = &pl[row + di][ch][0];
            float v[6];
            #pragma unroll
            for (int k = 0; k < 6; ++k) {
                int c = c0 - 1 + k;
                c = (c < 0 || c > 55) ? 56 : c;   // sentinel = 0
                v[k] = b2f(rp[c]);
            }
            #pragma unroll
            for (int cc2 = 0; cc2 < 4; ++cc2) {
                acc[cc2] += wreg[di * 3 + 0] * v[cc2];
                acc[cc2] += wreg[di * 3 + 1] * v[cc2 + 1];
                acc[cc2] += wreg[di * 3 + 2] * v[cc2 + 2];
            }
        }
        const int orow = i0 + row;
        #pragma unroll
        for (int cc2 = 0; cc2 < 4; ++cc2)
            out[(size_t)(b * HWP + orow * HH + c0 + cc2) * CC + cg * 32 + ch] = f2b(acc[cc2]);
    }
}

// ---------------------------------------------------------------------------
// MFMA GEMM:  OUT[oc][n] = sum_k WA[oc][k] * BT[n][k] + bias[oc]
// 128x128 tile, BK=32, 4 waves (2x2), 4x4 16x16x32 fragments per wave.
// OUT_BF16: bf16 [n][OC] pixel-major via LDS bounce.  else fp32 NCHW.
// ---------------------------------------------------------------------------
template <int OC, bool OUT_BF16>
__global__ __launch_bounds__(256) void pconv_mfma(const ushort* __restrict__ bt,
                                                  const ushort* __restrict__ wa,
                                                  const float* __restrict__ bias,
                                                  void* __restrict__ outv) {
    __shared__ __align__(16) char smem[OUT_BF16 ? 34816 : 16384];
    ushort (* const sA)[32] = (ushort(*)[32])smem;            // 128x32 weights
    ushort (* const sB)[32] = (ushort(*)[32])(smem + 8192);   // 128x32 inputs

    const int n0  = blockIdx.x * 128;
    const int oc0 = blockIdx.y * 128;
    const int t   = threadIdx.x;
    const int l   = t & 63;
    const int wm  = (t >> 6) >> 1, wn = (t >> 6) & 1;

    f32x4 acc[4][4] = {};

    const int cm0 = t >> 2,        ck0 = (t & 3) * 8;
    const int cm1 = (t + 256) >> 2, ck1 = ((t + 256) & 3) * 8;
    char* const ldsA = smem + (t & 192) * 16;          // wave-uniform base
    char* const ldsB = smem + 8192 + (t & 192) * 16;

    for (int k0 = 0; k0 < CC; k0 += 32) {
        __builtin_amdgcn_global_load_lds(
            (const __attribute__((address_space(1))) void*)(wa + (size_t)(oc0 + cm0) * CC + k0 + ck0),
            (__attribute__((address_space(3))) void*)ldsA, 16, 0, 0);
        __builtin_amdgcn_global_load_lds(
            (const __attribute__((address_space(1))) void*)(wa + (size_t)(oc0 + cm1) * CC + k0 + ck1),
            (__attribute__((address_space(3))) void*)(ldsA + 4096), 16, 0, 0);
        __builtin_amdgcn_global_load_lds(
            (const __attribute__((address_space(1))) void*)(bt + (size_t)(n0 + cm0) * CC + k0 + ck0),
            (__attribute__((address_space(3))) void*)ldsB, 16, 0, 0);
        __builtin_amdgcn_global_load_lds(
            (const __attribute__((address_space(1))) void*)(bt + (size_t)(n0 + cm1) * CC + k0 + ck1),
            (__attribute__((address_space(3))) void*)(ldsB + 4096), 16, 0, 0);
        __syncthreads();
        bf16x8 a[4], bb[4];
        #pragma unroll
        for (int i = 0; i < 4; ++i)
            a[i] = *(const bf16x8*)&sA[wm * 64 + i * 16 + (l & 15)][(l >> 4) * 8];
        #pragma unroll
        for (int i = 0; i < 4; ++i)
            bb[i] = *(const bf16x8*)&sB[wn * 64 + i * 16 + (l & 15)][(l >> 4) * 8];
        #pragma unroll
        for (int mf = 0; mf < 4; ++mf)
            #pragma unroll
            for (int nf = 0; nf < 4; ++nf)
                acc[mf][nf] = __builtin_amdgcn_mfma_f32_16x16x32_bf16(a[mf], bb[nf], acc[mf][nf], 0, 0, 0);
        __syncthreads();
    }

    const int rl = (l >> 4) * 4;   // fragment row base (oc dim)
    const int cl = l & 15;         // fragment col (n dim)
    if (OUT_BF16) {
        ushort (* const sD)[136] = (ushort(*)[136])smem;
        #pragma unroll
        for (int mf = 0; mf < 4; ++mf) {
            const int ocl = wm * 64 + mf * 16 + rl;
            #pragma unroll
            for (int nf = 0; nf < 4; ++nf) {
                const int nl = wn * 64 + nf * 16 + cl;
                ushort4 w4;
                w4.x = f2b(acc[mf][nf][0] + bias[oc0 + ocl + 0]);
                w4.y = f2b(acc[mf][nf][1] + bias[oc0 + ocl + 1]);
                w4.z = f2b(acc[mf][nf][2] + bias[oc0 + ocl + 2]);
                w4.w = f2b(acc[mf][nf][3] + bias[oc0 + ocl + 3]);
                *(ushort4*)&sD[nl][ocl] = w4;
            }
        }
        __syncthreads();
        ushort* outp = (ushort*)outv;
        #pragma unroll
        for (int rr = 0; rr < 8; ++rr) {
            const int r = (t >> 4) + rr * 16;
            const int c8 = (t & 15) * 8;
            *(uint4*)&outp[(size_t)(n0 + r) * C3 + oc0 + c8] = *(const uint4*)&sD[r][c8];
        }
    } else {
        float* outp = (float*)outv;
        #pragma unroll
        for (int mf = 0; mf < 4; ++mf) {
            const int row = oc0 + wm * 64 + mf * 16 + rl;
            #pragma unroll
            for (int r = 0; r < 4; ++r) {
                const float bs = bias[row + r];
                #pragma unroll
                for (int nf = 0; nf < 4; ++nf) {
                    const int n = n0 + wn * 64 + nf * 16 + cl;
                    const int b = n / HWP, p = n - b * HWP;
                    outp[((size_t)b * OC + row + r) * HWP + p] = acc[mf][nf][r] + bs;
                }
            }
        }
    }
}

// ---------------------------------------------------------------------------
// MFMA windowed attention.  qkv [n][1152] bf16 -> att [n][384] bf16.
// One wave per (window, head): S^T = mfma(K,Q) padded 49->64, in-register
// softmax (in-lane 16 + shfl_xor 16/32), P -> LDS bf16, PV = mfma(P, V^T)
// with chunk-XOR-swizzled V tile, O bounced through P tile for uint4 stores.
// Grid (64 windows, 3 head-groups, 16 b), 256 threads = 4 waves (4 heads).
// ---------------------------------------------------------------------------
__global__ __launch_bounds__(256) void attn_mfma(const ushort* __restrict__ qkv,
                                                 const float* __restrict__ pos,
                                                 ushort* __restrict__ out) {
    __shared__ float sPb[169];
    __shared__ __align__(16) ushort sV[4][64 * 40];    // per-wave V [pix][d] swizzled
    __shared__ __align__(16) ushort sPl[4][64 * 72];   // per-wave P, then O bounce

    const int w = blockIdx.x, hg = blockIdx.y, b = blockIdx.z;
    const int wr = w >> 3, wc = w & 7;
    const int t = threadIdx.x, ww = t >> 6, l = t & 63;
    const int h = hg * 4 + ww;
    const int i15 = l & 15, g = l >> 4;
    const int hch = h * HD;
    if (t < 169) sPb[t] = pos[t];
    ushort* const sVw = sV[ww];
    ushort* const sPw = sPl[ww];

    // ---- stage V (rows 49..63 zeroed), chunk-XOR swizzle on d-chunks ----
    #pragma unroll
    for (int pass = 0; pass < 4; ++pass) {
        const int e = l + pass * 64;
        const int pix = e >> 2, c8 = e & 3;
        uint4 v = make_uint4(0, 0, 0, 0);
        if (pix < WSQ) {
            const int n = b * HWP + (wr * WSZ + pix / 7) * HH + wc * WSZ + pix % 7;
            v = *(const uint4*)&qkv[(size_t)n * C3 + 2 * CC + hch + c8 * 8];
        }
        const int cst = c8 ^ ((pix >> 2) & 3);
        *(uint4*)&sVw[pix * 40 + cst * 8] = v;
    }

    // ---- Q (B-frag) and K (A-frag) direct from global, zero-padded ----
    bf16x8 qf[4], kf[4];
    #pragma unroll
    for (int it = 0; it < 4; ++it) {
        const int i = it * 16 + i15;
        U128 uq, uk;
        uq.u = make_uint4(0, 0, 0, 0);
        uk.u = make_uint4(0, 0, 0, 0);
        if (i < WSQ) {
            const int n = b * HWP + (wr * WSZ + i / 7) * HH + wc * WSZ + i % 7;
            uq.u = *(const uint4*)&qkv[(size_t)n * C3 + hch + g * 8];
            uk.u = *(const uint4*)&qkv[(size_t)n * C3 + CC + hch + g * 8];
        }
        qf[it] = uq.v;
        kf[it] = uk.v;
    }

    // ---- S^T = K·Q^T : D[j][i], lane holds i = it*16+i15, j = jt*16+4g+r ----
    f32x4 sS[4][4] = {};
    #pragma unroll
    for (int jt = 0; jt < 4; ++jt)
        #pragma unroll
        for (int it = 0; it < 4; ++it)
            sS[jt][it] = __builtin_amdgcn_mfma_f32_16x16x32_bf16(kf[jt], qf[it], sS[jt][it], 0, 0, 0);

    __syncthreads();   // sPb ready (block-wide); per-wave LDS needs no barrier

    // ---- fold scale + rel-pos bias + shift mask ----
    #pragma unroll
    for (int jt = 0; jt < 4; ++jt) {
        #pragma unroll
        for (int r = 0; r < 4; ++r) {
            const int j = jt * 16 + 4 * g + r;
            const bool jv = j < WSQ;
            const int pjr = j / 7, pjc = j % 7;
            #pragma unroll
            for (int it = 0; it < 4; ++it) {
                const int i = it * 16 + i15;
                float s = -1e30f;
                if ((i < WSQ) && jv) {
                    const int pir = i / 7, pic = i % 7;
                    s = sS[jt][it][r] * DKS + sPb[(pjr - pir + 6) * 13 + (pjc - pic + 6)];
                    if ((wr == 7 && ((pir >= 4) != (pjr >= 4))) ||
                        (wc == 7 && ((pic >= 4) != (pjc >= 4)))) s = -1e30f;
                }
                sS[jt][it][r] = s;
            }
        }
    }

    // ---- softmax over j per column i: 16 in-lane + lanes l^16, l^32 ----
    #pragma unroll
    for (int it = 0; it < 4; ++it) {
        float m = -1e30f;
        #pragma unroll
        for (int jt = 0; jt < 4; ++jt)
            #pragma unroll
            for (int r = 0; r < 4; ++r) m = fmaxf(m, sS[jt][it][r]);
        m = fmaxf(m, __shfl_xor(m, 16));
        m = fmaxf(m, __shfl_xor(m, 32));
        float sum = 0.f;
        #pragma unroll
        for (int jt = 0; jt < 4; ++jt)
            #pragma unroll
            for (int r = 0; r < 4; ++r) {
                const float e2 = __expf(sS[jt][it][r] - m);
                sS[jt][it][r] = e2;
                sum += e2;
            }
        sum += __shfl_xor(sum, 16);
        sum += __shfl_xor(sum, 32);
        const float inv = 1.f / sum;
        #pragma unroll
        for (int jt = 0; jt < 4; ++jt)
            #pragma unroll
            for (int r = 0; r < 4; ++r) sS[jt][it][r] *= inv;
    }

    // ---- pack P to bf16, write P_lds[i][j] (pad 72) ----
    #pragma unroll
    for (int it = 0; it < 4; ++it) {
        const int i = it * 16 + i15;
        #pragma unroll
        for (int jt = 0; jt < 4; ++jt) {
            const uint lo = (uint)f2b(sS[jt][it][0]) | ((uint)f2b(sS[jt][it][1]) << 16);
            const uint hi = (uint)f2b(sS[jt][it][2]) | ((uint)f2b(sS[jt][it][3]) << 16);
            *(uint2*)&sPw[i * 72 + jt * 16 + 4 * g] = make_uint2(lo, hi);
        }
    }

    // ---- PV: O[i][d] = sum_j P[i][j] V[j][d] ----
    f32x4 oacc[4][2] = {};
    #pragma unroll
    for (int kt = 0; kt < 2; ++kt) {
        bf16x8 pa[4];
        #pragma unroll
        for (int mt = 0; mt < 4; ++mt)
            pa[mt] = *(const bf16x8*)&sPw[(mt * 16 + i15) * 72 + kt * 32 + g * 8];
        bf16x8 bv[2];
        #pragma unroll
        for (int nt = 0; nt < 2; ++nt) {
            U128 u;
            #pragma unroll
            for (int s = 0; s < 8; ++s) {
                const int j = kt * 32 + 8 * g + s;
                const int d = nt * 16 + i15;
                const int cp = (d >> 3) ^ ((j >> 2) & 3);
                u.us[s] = sVw[j * 40 + cp * 8 + (d & 7)];
            }
            bv[nt] = u.v;
        }
        #pragma unroll
        for (int mt = 0; mt < 4; ++mt)
            #pragma unroll
            for (int nt = 0; nt < 2; ++nt)
                oacc[mt][nt] = __builtin_amdgcn_mfma_f32_16x16x32_bf16(pa[mt], bv[nt], oacc[mt][nt], 0, 0, 0);
    }

    // ---- O bounce through sPw (pad 40, chunk-XOR by (i>>2)&3) ----
    #pragma unroll
    for (int mt = 0; mt < 4; ++mt)
        #pragma unroll
        for (int nt = 0; nt < 2; ++nt)
            #pragma unroll
            for (int r = 0; r < 4; ++r) {
                const int i = mt * 16 + 4 * g + r;
                const int d = nt * 16 + i15;
                const int cp = (d >> 3) ^ ((i >> 2) & 3);
                sPw[i * 40 + cp * 8 + (d & 7)] = f2b(oacc[mt][nt][r]);
            }

    // ---- coalesced readout ----
    #pragma unroll
    for (int pass = 0; pass < 4; ++pass) {
        const int e = l + pass * 64;
        const int pix = e >> 2, c8 = e & 3;
        if (pix < WSQ) {
            const int n = b * HWP + (wr * WSZ + pix / 7) * HH + wc * WSZ + pix % 7;
            const int cp = c8 ^ ((pix >> 2) & 3);
            *(uint4*)&out[(size_t)n * CC + hch + c8 * 8] = *(const uint4*)&sPw[pix * 40 + cp * 8];
        }
    }
}

// ---------------------------------------------------------------------------
extern "C" void kernel_launch(void* const* d_in, const int* in_sizes, int n_in,
                              void* d_out, int out_size, void* d_ws, size_t ws_size,
                              hipStream_t stream) {
    const float* x      = (const float*)d_in[0];
    const float* qkv_dw = (const float*)d_in[1];
    const float* qkv_pw = (const float*)d_in[2];
    const float* qkv_pb = (const float*)d_in[3];
    const float* out_dw = (const float*)d_in[4];
    const float* out_pw = (const float*)d_in[5];
    const float* out_pb = (const float*)d_in[6];
    const float* pos    = (const float*)d_in[7];

    // ws: A [NTOT][384] | B [NTOT][1152] | wA1 [1152][384] | wA2 [384][384]
    ushort* A   = (ushort*)d_ws;
    ushort* B   = A + (size_t)NTOT * CC;
    ushort* wA1 = B + (size_t)NTOT * C3;
    ushort* wA2 = wA1 + (size_t)C3 * CC;

    cvt_bf16<<<(C3 * CC + 255) / 256, 256, 0, stream>>>(qkv_pw, wA1, C3 * CC);
    cvt_bf16<<<(CC * CC + 255) / 256, 256, 0, stream>>>(out_pw, wA2, CC * CC);

    // 1) roll(-3) + depthwise -> A [n][384] bf16
    dconv_px<false><<<dim3(14, 12, BQ), 256, 0, stream>>>(x, qkv_dw, A, 3);
    // 2) pointwise 384->1152 -> B [n][1152] bf16
    pconv_mfma<C3, true><<<dim3(NTOT / 128, C3 / 128), 256, 0, stream>>>(A, wA1, qkv_pb, B);
    // 3) windowed attention -> A [n][384] bf16
    attn_mfma<<<dim3(NWIN, NHEAD / 4, BQ), 256, 0, stream>>>(B, pos, A);
    // 4) roll(+3) + depthwise -> B (reused) [n][384] bf16
    dconv_px<true><<<dim3(14, 12, BQ), 256, 0, stream>>>(A, out_dw, B, 53);
    // 5) pointwise 384->384 -> d_out fp32 NCHW
    pconv_mfma<CC, false><<<dim3(NTOT / 128, CC / 128), 256, 0, stream>>>(B, wA2, out_pb, (float*)d_out);
}

// Round 11
// 268.458 us; speedup vs baseline: 4.6083x; 1.0611x over previous
//
#include <hip/hip_runtime.h>
#include <hip/hip_bf16.h>
#include <cstddef>
#include <cstdint>

#define BQ    16
#define CC    384
#define C3    1152
#define HH    56
#define HWP   3136
#define NTOT  (BQ * HWP)   // 50176
#define NHEAD 12
#define HD    32
#define WSZ   7
#define NWIN  64
#define WSQ   49
#define DKS   0.17677669529663687f

typedef __attribute__((ext_vector_type(8))) short bf16x8;
typedef __attribute__((ext_vector_type(4))) float f32x4;

union U128 { uint4 u; bf16x8 v; ushort us[8]; };

__device__ __forceinline__ ushort f2b(float f) {
    __hip_bfloat16 h = __float2bfloat16(f);
    return *reinterpret_cast<ushort*>(&h);
}
__device__ __forceinline__ float b2f(ushort u) {
    __hip_bfloat16 h;
    *reinterpret_cast<ushort*>(&h) = u;
    return __bfloat162float(h);
}

__global__ void cvt_bf16(const float* __restrict__ in, ushort* __restrict__ out, int n) {
    const int i = blockIdx.x * 256 + threadIdx.x;
    if (i < n) out[i] = f2b(in[i]);
}

// ---------------------------------------------------------------------------
// roll + depthwise 3x3, pixel-major output [n][384].  (unchanged from r9)
// ---------------------------------------------------------------------------
template <bool BF16IN>
__global__ __launch_bounds__(256) void dconv_px(const void* __restrict__ inv,
                                                const float* __restrict__ dw,
                                                ushort* __restrict__ out,
                                                int shiftAdd) {
    __shared__ ushort pl[6][32][57];
    const int band = blockIdx.x, cg = blockIdx.y, b = blockIdx.z;
    const int i0 = band * 4;
    const int t = threadIdx.x;
    const int ch = t & 31;

    float wreg[9];
    #pragma unroll
    for (int k = 0; k < 9; ++k) wreg[k] = dw[(cg * 32 + ch) * 9 + k];

    if (t < 192) pl[t >> 5][t & 31][56] = 0;

    if (BF16IN) {
        const ushort* src = (const ushort*)inv;
        const int c8 = t & 3, col = t >> 2;
        if (col < 56) {
            int cc = col + shiftAdd; if (cc >= HH) cc -= HH;
            #pragma unroll
            for (int lr = 0; lr < 6; ++lr) {
                const int gi = i0 + lr - 1;
                U128 u; u.u = make_uint4(0, 0, 0, 0);
                if (gi >= 0 && gi < HH) {
                    int rr = gi + shiftAdd; if (rr >= HH) rr -= HH;
                    u.u = *(const uint4*)&src[(size_t)(b * HWP + rr * HH + cc) * CC + cg * 32 + c8 * 8];
                }
                #pragma unroll
                for (int k = 0; k < 8; ++k) pl[lr][c8 * 8 + k][col] = u.us[k];
            }
        }
    } else {
        const float* src = (const float*)inv;
        const int col = t & 63, q0 = t >> 6;
        if (col < 56) {
            int cc = col + shiftAdd; if (cc >= HH) cc -= HH;
            #pragma unroll 8
            for (int p = 0; p < 48; ++p) {
                const int q = q0 + p * 4;
                const int lc = q & 31, lr = q >> 5;
                const int gi = i0 + lr - 1;
                ushort v = 0;
                if (gi >= 0 && gi < HH) {
                    int rr = gi + shiftAdd; if (rr >= HH) rr -= HH;
                    v = f2b(src[((size_t)(b * CC + cg * 32 + lc)) * HWP + rr * HH + cc]);
                }
                pl[lr][lc][col] = v;
            }
        }
    }
    __syncthreads();

    const int u = t >> 5;
    #pragma unroll
    for (int iter = 0; iter < 7; ++iter) {
        const int unit = iter * 8 + u;
        const int colb = unit >> 2;
        const int row  = unit & 3;
        const int c0 = colb * 4;
        float acc[4] = {0.f, 0.f, 0.f, 0.f};
        #pragma unroll
        for (int di = 0; di < 3; ++di) {
            const ushort* rp = &pl[row + di][ch][0];
            float v[6];
            #pragma unroll
            for (int k = 0; k < 6; ++k) {
                int c = c0 - 1 + k;
                c = (c < 0 || c > 55) ? 56 : c;   // sentinel = 0
                v[k] = b2f(rp[c]);
            }
            #pragma unroll
            for (int cc2 = 0; cc2 < 4; ++cc2) {
                acc[cc2] += wreg[di * 3 + 0] * v[cc2];
                acc[cc2] += wreg[di * 3 + 1] * v[cc2 + 1];
                acc[cc2] += wreg[di * 3 + 2] * v[cc2 + 2];
            }
        }
        const int orow = i0 + row;
        #pragma unroll
        for (int cc2 = 0; cc2 < 4; ++cc2)
            out[(size_t)(b * HWP + orow * HH + c0 + cc2) * CC + cg * 32 + ch] = f2b(acc[cc2]);
    }
}

// ---------------------------------------------------------------------------
// MFMA GEMM:  OUT[oc][n] = sum_k WA[oc][k] * BT[n][k] + bias[oc]
// 128x128 tile, BK=32, 2-phase double-buffered prefetch (counted vmcnt,
// raw s_barrier), XOR-swizzled staging source + swizzled ds_read (rule 21).
// Grid (OC/128, NTOT/128): oc fastest -> consecutive blocks share the
// activation panel (FETCH locality).
// OUT_BF16: bf16 [n][OC] pixel-major via LDS bounce.  else fp32 NCHW.
// ---------------------------------------------------------------------------
template <int OC, bool OUT_BF16>
__global__ __launch_bounds__(256) void pconv_mfma(const ushort* __restrict__ bt,
                                                  const ushort* __restrict__ wa,
                                                  const float* __restrict__ bias,
                                                  void* __restrict__ outv) {
    // dbuf: A0@0 B0@8192 A1@16384 B1@24576 (32 KB); epilogue sD overlays.
    __shared__ __align__(16) char smem[OUT_BF16 ? 34816 : 32768];

    const int oc0 = blockIdx.x * 128;
    const int n0  = blockIdx.y * 128;
    const int t   = threadIdx.x;
    const int l   = t & 63;
    const int wm  = (t >> 6) >> 1, wn = (t >> 6) & 1;
    const int i15 = l & 15, g = l >> 4;

    f32x4 acc[4][4] = {};

    // staging: thread t owns chunks t (rows 0..63) and t+256 (rows 64..127);
    // physical slot (t&3) holds logical k-chunk (t&3)^((row>>1)&3).
    const int r0 = t >> 2;
    const int kc = ((t & 3) ^ ((t >> 3) & 3)) * 8;   // pre-swizzled k offset
    const size_t gA0 = (size_t)(oc0 + r0) * CC + kc;
    const size_t gA1 = (size_t)(oc0 + r0 + 64) * CC + kc;
    const size_t gB0 = (size_t)(n0 + r0) * CC + kc;
    const size_t gB1 = (size_t)(n0 + r0 + 64) * CC + kc;
    const int ldsOff = (t & 192) * 16;               // wave-uniform base

#define STAGE(buf, k0) do {                                                              \
    char* la_ = smem + (buf) * 16384 + ldsOff;                                           \
    char* lb_ = la_ + 8192;                                                              \
    __builtin_amdgcn_global_load_lds(                                                    \
        (const __attribute__((address_space(1))) void*)(wa + gA0 + (k0)),                \
        (__attribute__((address_space(3))) void*)la_, 16, 0, 0);                         \
    __builtin_amdgcn_global_load_lds(                                                    \
        (const __attribute__((address_space(1))) void*)(wa + gA1 + (k0)),                \
        (__attribute__((address_space(3))) void*)(la_ + 4096), 16, 0, 0);                \
    __builtin_amdgcn_global_load_lds(                                                    \
        (const __attribute__((address_space(1))) void*)(bt + gB0 + (k0)),                \
        (__attribute__((address_space(3))) void*)lb_, 16, 0, 0);                         \
    __builtin_amdgcn_global_load_lds(                                                    \
        (const __attribute__((address_space(1))) void*)(bt + gB1 + (k0)),                \
        (__attribute__((address_space(3))) void*)(lb_ + 4096), 16, 0, 0);                \
} while (0)

    // fragment read addressing (same XOR as staging)
    const int colb = (g ^ ((i15 >> 1) & 3)) << 4;
    const int rbA = (wm * 64 + i15) * 64 + colb;     // + i*1024 per fragment
    const int rbB = (wn * 64 + i15) * 64 + colb;

    STAGE(0, 0);
    int cur = 0;
    for (int kt = 0; kt < 12; ++kt) {
        if (kt < 11) {
            STAGE(cur ^ 1, (kt + 1) * 32);
            asm volatile("s_waitcnt vmcnt(4)" ::: "memory");  // cur's 4 done; next 4 fly
        } else {
            asm volatile("s_waitcnt vmcnt(0)" ::: "memory");
        }
        __builtin_amdgcn_s_barrier();
        const char* bufA = smem + cur * 16384;
        const char* bufB = bufA + 8192;
        bf16x8 a[4], bb[4];
        #pragma unroll
        for (int i = 0; i < 4; ++i) {
            a[i]  = *(const bf16x8*)(bufA + rbA + i * 1024);
            bb[i] = *(const bf16x8*)(bufB + rbB + i * 1024);
        }
        #pragma unroll
        for (int mf = 0; mf < 4; ++mf)
            #pragma unroll
            for (int nf = 0; nf < 4; ++nf)
                acc[mf][nf] = __builtin_amdgcn_mfma_f32_16x16x32_bf16(a[mf], bb[nf], acc[mf][nf], 0, 0, 0);
        __builtin_amdgcn_sched_barrier(0);           // pin reads/MFMA before barrier
        __builtin_amdgcn_s_barrier();
        cur ^= 1;
    }
#undef STAGE

    const int rl = (l >> 4) * 4;   // fragment row base (oc dim)
    const int cl = l & 15;         // fragment col (n dim)
    if (OUT_BF16) {
        ushort (* const sD)[136] = (ushort(*)[136])smem;
        #pragma unroll
        for (int mf = 0; mf < 4; ++mf) {
            const int ocl = wm * 64 + mf * 16 + rl;
            #pragma unroll
            for (int nf = 0; nf < 4; ++nf) {
                const int nl = wn * 64 + nf * 16 + cl;
                ushort4 w4;
                w4.x = f2b(acc[mf][nf][0] + bias[oc0 + ocl + 0]);
                w4.y = f2b(acc[mf][nf][1] + bias[oc0 + ocl + 1]);
                w4.z = f2b(acc[mf][nf][2] + bias[oc0 + ocl + 2]);
                w4.w = f2b(acc[mf][nf][3] + bias[oc0 + ocl + 3]);
                *(ushort4*)&sD[nl][ocl] = w4;
            }
        }
        __syncthreads();
        ushort* outp = (ushort*)outv;
        #pragma unroll
        for (int rr = 0; rr < 8; ++rr) {
            const int r = (t >> 4) + rr * 16;
            const int c8 = (t & 15) * 8;
            *(uint4*)&outp[(size_t)(n0 + r) * C3 + oc0 + c8] = *(const uint4*)&sD[r][c8];
        }
    } else {
        float* outp = (float*)outv;
        #pragma unroll
        for (int mf = 0; mf < 4; ++mf) {
            const int row = oc0 + wm * 64 + mf * 16 + rl;
            #pragma unroll
            for (int r = 0; r < 4; ++r) {
                const float bs = bias[row + r];
                #pragma unroll
                for (int nf = 0; nf < 4; ++nf) {
                    const int n = n0 + wn * 64 + nf * 16 + cl;
                    const int b = n / HWP, p = n - b * HWP;
                    outp[((size_t)b * OC + row + r) * HWP + p] = acc[mf][nf][r] + bs;
                }
            }
        }
    }
}

// ---------------------------------------------------------------------------
// MFMA windowed attention.  (unchanged from r9)
// ---------------------------------------------------------------------------
__global__ __launch_bounds__(256) void attn_mfma(const ushort* __restrict__ qkv,
                                                 const float* __restrict__ pos,
                                                 ushort* __restrict__ out) {
    __shared__ float sPb[169];
    __shared__ __align__(16) ushort sV[4][64 * 40];
    __shared__ __align__(16) ushort sPl[4][64 * 72];

    const int w = blockIdx.x, hg = blockIdx.y, b = blockIdx.z;
    const int wr = w >> 3, wc = w & 7;
    const int t = threadIdx.x, ww = t >> 6, l = t & 63;
    const int h = hg * 4 + ww;
    const int i15 = l & 15, g = l >> 4;
    const int hch = h * HD;
    if (t < 169) sPb[t] = pos[t];
    ushort* const sVw = sV[ww];
    ushort* const sPw = sPl[ww];

    #pragma unroll
    for (int pass = 0; pass < 4; ++pass) {
        const int e = l + pass * 64;
        const int pix = e >> 2, c8 = e & 3;
        uint4 v = make_uint4(0, 0, 0, 0);
        if (pix < WSQ) {
            const int n = b * HWP + (wr * WSZ + pix / 7) * HH + wc * WSZ + pix % 7;
            v = *(const uint4*)&qkv[(size_t)n * C3 + 2 * CC + hch + c8 * 8];
        }
        const int cst = c8 ^ ((pix >> 2) & 3);
        *(uint4*)&sVw[pix * 40 + cst * 8] = v;
    }

    bf16x8 qf[4], kf[4];
    #pragma unroll
    for (int it = 0; it < 4; ++it) {
        const int i = it * 16 + i15;
        U128 uq, uk;
        uq.u = make_uint4(0, 0, 0, 0);
        uk.u = make_uint4(0, 0, 0, 0);
        if (i < WSQ) {
            const int n = b * HWP + (wr * WSZ + i / 7) * HH + wc * WSZ + i % 7;
            uq.u = *(const uint4*)&qkv[(size_t)n * C3 + hch + g * 8];
            uk.u = *(const uint4*)&qkv[(size_t)n * C3 + CC + hch + g * 8];
        }
        qf[it] = uq.v;
        kf[it] = uk.v;
    }

    f32x4 sS[4][4] = {};
    #pragma unroll
    for (int jt = 0; jt < 4; ++jt)
        #pragma unroll
        for (int it = 0; it < 4; ++it)
            sS[jt][it] = __builtin_amdgcn_mfma_f32_16x16x32_bf16(kf[jt], qf[it], sS[jt][it], 0, 0, 0);

    __syncthreads();

    #pragma unroll
    for (int jt = 0; jt < 4; ++jt) {
        #pragma unroll
        for (int r = 0; r < 4; ++r) {
            const int j = jt * 16 + 4 * g + r;
            const bool jv = j < WSQ;
            const int pjr = j / 7, pjc = j % 7;
            #pragma unroll
            for (int it = 0; it < 4; ++it) {
                const int i = it * 16 + i15;
                float s = -1e30f;
                if ((i < WSQ) && jv) {
                    const int pir = i / 7, pic = i % 7;
                    s = sS[jt][it][r] * DKS + sPb[(pjr - pir + 6) * 13 + (pjc - pic + 6)];
                    if ((wr == 7 && ((pir >= 4) != (pjr >= 4))) ||
                        (wc == 7 && ((pic >= 4) != (pjc >= 4)))) s = -1e30f;
                }
                sS[jt][it][r] = s;
            }
        }
    }

    #pragma unroll
    for (int it = 0; it < 4; ++it) {
        float m = -1e30f;
        #pragma unroll
        for (int jt = 0; jt < 4; ++jt)
            #pragma unroll
            for (int r = 0; r < 4; ++r) m = fmaxf(m, sS[jt][it][r]);
        m = fmaxf(m, __shfl_xor(m, 16));
        m = fmaxf(m, __shfl_xor(m, 32));
        float sum = 0.f;
        #pragma unroll
        for (int jt = 0; jt < 4; ++jt)
            #pragma unroll
            for (int r = 0; r < 4; ++r) {
                const float e2 = __expf(sS[jt][it][r] - m);
                sS[jt][it][r] = e2;
                sum += e2;
            }
        sum += __shfl_xor(sum, 16);
        sum += __shfl_xor(sum, 32);
        const float inv = 1.f / sum;
        #pragma unroll
        for (int jt = 0; jt < 4; ++jt)
            #pragma unroll
            for (int r = 0; r < 4; ++r) sS[jt][it][r] *= inv;
    }

    #pragma unroll
    for (int it = 0; it < 4; ++it) {
        const int i = it * 16 + i15;
        #pragma unroll
        for (int jt = 0; jt < 4; ++jt) {
            const uint lo = (uint)f2b(sS[jt][it][0]) | ((uint)f2b(sS[jt][it][1]) << 16);
            const uint hi = (uint)f2b(sS[jt][it][2]) | ((uint)f2b(sS[jt][it][3]) << 16);
            *(uint2*)&sPw[i * 72 + jt * 16 + 4 * g] = make_uint2(lo, hi);
        }
    }

    f32x4 oacc[4][2] = {};
    #pragma unroll
    for (int kt = 0; kt < 2; ++kt) {
        bf16x8 pa[4];
        #pragma unroll
        for (int mt = 0; mt < 4; ++mt)
            pa[mt] = *(const bf16x8*)&sPw[(mt * 16 + i15) * 72 + kt * 32 + g * 8];
        bf16x8 bv[2];
        #pragma unroll
        for (int nt = 0; nt < 2; ++nt) {
            U128 u;
            #pragma unroll
            for (int s = 0; s < 8; ++s) {
                const int j = kt * 32 + 8 * g + s;
                const int d = nt * 16 + i15;
                const int cp = (d >> 3) ^ ((j >> 2) & 3);
                u.us[s] = sVw[j * 40 + cp * 8 + (d & 7)];
            }
            bv[nt] = u.v;
        }
        #pragma unroll
        for (int mt = 0; mt < 4; ++mt)
            #pragma unroll
            for (int nt = 0; nt < 2; ++nt)
                oacc[mt][nt] = __builtin_amdgcn_mfma_f32_16x16x32_bf16(pa[mt], bv[nt], oacc[mt][nt], 0, 0, 0);
    }

    #pragma unroll
    for (int mt = 0; mt < 4; ++mt)
        #pragma unroll
        for (int nt = 0; nt < 2; ++nt)
            #pragma unroll
            for (int r = 0; r < 4; ++r) {
                const int i = mt * 16 + 4 * g + r;
                const int d = nt * 16 + i15;
                const int cp = (d >> 3) ^ ((i >> 2) & 3);
                sPw[i * 40 + cp * 8 + (d & 7)] = f2b(oacc[mt][nt][r]);
            }

    #pragma unroll
    for (int pass = 0; pass < 4; ++pass) {
        const int e = l + pass * 64;
        const int pix = e >> 2, c8 = e & 3;
        if (pix < WSQ) {
            const int n = b * HWP + (wr * WSZ + pix / 7) * HH + wc * WSZ + pix % 7;
            const int cp = c8 ^ ((pix >> 2) & 3);
            *(uint4*)&out[(size_t)n * CC + hch + c8 * 8] = *(const uint4*)&sPw[pix * 40 + cp * 8];
        }
    }
}

// ---------------------------------------------------------------------------
extern "C" void kernel_launch(void* const* d_in, const int* in_sizes, int n_in,
                              void* d_out, int out_size, void* d_ws, size_t ws_size,
                              hipStream_t stream) {
    const float* x      = (const float*)d_in[0];
    const float* qkv_dw = (const float*)d_in[1];
    const float* qkv_pw = (const float*)d_in[2];
    const float* qkv_pb = (const float*)d_in[3];
    const float* out_dw = (const float*)d_in[4];
    const float* out_pw = (const float*)d_in[5];
    const float* out_pb = (const float*)d_in[6];
    const float* pos    = (const float*)d_in[7];

    // ws: A [NTOT][384] | B [NTOT][1152] | wA1 [1152][384] | wA2 [384][384]
    ushort* A   = (ushort*)d_ws;
    ushort* B   = A + (size_t)NTOT * CC;
    ushort* wA1 = B + (size_t)NTOT * C3;
    ushort* wA2 = wA1 + (size_t)C3 * CC;

    cvt_bf16<<<(C3 * CC + 255) / 256, 256, 0, stream>>>(qkv_pw, wA1, C3 * CC);
    cvt_bf16<<<(CC * CC + 255) / 256, 256, 0, stream>>>(out_pw, wA2, CC * CC);

    // 1) roll(-3) + depthwise -> A [n][384] bf16
    dconv_px<false><<<dim3(14, 12, BQ), 256, 0, stream>>>(x, qkv_dw, A, 3);
    // 2) pointwise 384->1152 -> B [n][1152] bf16  (oc-fastest grid)
    pconv_mfma<C3, true><<<dim3(C3 / 128, NTOT / 128), 256, 0, stream>>>(A, wA1, qkv_pb, B);
    // 3) windowed attention -> A [n][384] bf16
    attn_mfma<<<dim3(NWIN, NHEAD / 4, BQ), 256, 0, stream>>>(B, pos, A);
    // 4) roll(+3) + depthwise -> B (reused) [n][384] bf16
    dconv_px<true><<<dim3(14, 12, BQ), 256, 0, stream>>>(A, out_dw, B, 53);
    // 5) pointwise 384->384 -> d_out fp32 NCHW  (oc-fastest grid)
    pconv_mfma<CC, false><<<dim3(CC / 128, NTOT / 128), 256, 0, stream>>>(B, wA2, out_pb, (float*)d_out);
}

// Round 13
// 262.522 us; speedup vs baseline: 4.7125x; 1.0226x over previous
//
#include <hip/hip_runtime.h>
#include <hip/hip_bf16.h>
#include <cstddef>
#include <cstdint>

#define BQ    16
#define CC    384
#define C3    1152
#define HH    56
#define HWP   3136
#define NTOT  (BQ * HWP)   // 50176
#define NHEAD 12
#define HD    32
#define WSZ   7
#define NWIN  64
#define WSQ   49
#define DKS   0.17677669529663687f

typedef __attribute__((ext_vector_type(8))) short bf16x8;
typedef __attribute__((ext_vector_type(4))) float f32x4;

union U128 { uint4 u; bf16x8 v; ushort us[8]; uint ui[4]; };

__device__ __forceinline__ ushort f2b(float f) {
    __hip_bfloat16 h = __float2bfloat16(f);
    return *reinterpret_cast<ushort*>(&h);
}
__device__ __forceinline__ float b2f(ushort u) {
    __hip_bfloat16 h;
    *reinterpret_cast<ushort*>(&h) = u;
    return __bfloat162float(h);
}

__global__ void cvt_bf16(const float* __restrict__ in, ushort* __restrict__ out, int n) {
    const int i = blockIdx.x * 256 + threadIdx.x;
    if (i < n) out[i] = f2b(in[i]);
}

// ---------------------------------------------------------------------------
// roll + depthwise 3x3, pixel-major output [n][384].  (unchanged from r9)
// ---------------------------------------------------------------------------
template <bool BF16IN>
__global__ __launch_bounds__(256) void dconv_px(const void* __restrict__ inv,
                                                const float* __restrict__ dw,
                                                ushort* __restrict__ out,
                                                int shiftAdd) {
    __shared__ ushort pl[6][32][57];
    const int band = blockIdx.x, cg = blockIdx.y, b = blockIdx.z;
    const int i0 = band * 4;
    const int t = threadIdx.x;
    const int ch = t & 31;

    float wreg[9];
    #pragma unroll
    for (int k = 0; k < 9; ++k) wreg[k] = dw[(cg * 32 + ch) * 9 + k];

    if (t < 192) pl[t >> 5][t & 31][56] = 0;

    if (BF16IN) {
        const ushort* src = (const ushort*)inv;
        const int c8 = t & 3, col = t >> 2;
        if (col < 56) {
            int cc = col + shiftAdd; if (cc >= HH) cc -= HH;
            #pragma unroll
            for (int lr = 0; lr < 6; ++lr) {
                const int gi = i0 + lr - 1;
                U128 u; u.u = make_uint4(0, 0, 0, 0);
                if (gi >= 0 && gi < HH) {
                    int rr = gi + shiftAdd; if (rr >= HH) rr -= HH;
                    u.u = *(const uint4*)&src[(size_t)(b * HWP + rr * HH + cc) * CC + cg * 32 + c8 * 8];
                }
                #pragma unroll
                for (int k = 0; k < 8; ++k) pl[lr][c8 * 8 + k][col] = u.us[k];
            }
        }
    } else {
        const float* src = (const float*)inv;
        const int col = t & 63, q0 = t >> 6;
        if (col < 56) {
            int cc = col + shiftAdd; if (cc >= HH) cc -= HH;
            #pragma unroll 8
            for (int p = 0; p < 48; ++p) {
                const int q = q0 + p * 4;
                const int lc = q & 31, lr = q >> 5;
                const int gi = i0 + lr - 1;
                ushort v = 0;
                if (gi >= 0 && gi < HH) {
                    int rr = gi + shiftAdd; if (rr >= HH) rr -= HH;
                    v = f2b(src[((size_t)(b * CC + cg * 32 + lc)) * HWP + rr * HH + cc]);
                }
                pl[lr][lc][col] = v;
            }
        }
    }
    __syncthreads();

    const int u = t >> 5;
    #pragma unroll
    for (int iter = 0; iter < 7; ++iter) {
        const int unit = iter * 8 + u;
        const int colb = unit >> 2;
        const int row  = unit & 3;
        const int c0 = colb * 4;
        float acc[4] = {0.f, 0.f, 0.f, 0.f};
        #pragma unroll
        for (int di = 0; di < 3; ++di) {
            const ushort* rp = &pl[row + di][ch][0];
            float v[6];
            #pragma unroll
            for (int k = 0; k < 6; ++k) {
                int c = c0 - 1 + k;
                c = (c < 0 || c > 55) ? 56 : c;   // sentinel = 0
                v[k] = b2f(rp[c]);
            }
            #pragma unroll
            for (int cc2 = 0; cc2 < 4; ++cc2) {
                acc[cc2] += wreg[di * 3 + 0] * v[cc2];
                acc[cc2] += wreg[di * 3 + 1] * v[cc2 + 1];
                acc[cc2] += wreg[di * 3 + 2] * v[cc2 + 2];
            }
        }
        const int orow = i0 + row;
        #pragma unroll
        for (int cc2 = 0; cc2 < 4; ++cc2)
            out[(size_t)(b * HWP + orow * HH + c0 + cc2) * CC + cg * 32 + ch] = f2b(acc[cc2]);
    }
}

// ---------------------------------------------------------------------------
// MFMA GEMM.  (unchanged from r11: 2-phase dbuf, counted vmcnt, XOR swizzle,
// oc-fastest grid)
// ---------------------------------------------------------------------------
template <int OC, bool OUT_BF16>
__global__ __launch_bounds__(256) void pconv_mfma(const ushort* __restrict__ bt,
                                                  const ushort* __restrict__ wa,
                                                  const float* __restrict__ bias,
                                                  void* __restrict__ outv) {
    __shared__ __align__(16) char smem[OUT_BF16 ? 34816 : 32768];

    const int oc0 = blockIdx.x * 128;
    const int n0  = blockIdx.y * 128;
    const int t   = threadIdx.x;
    const int l   = t & 63;
    const int wm  = (t >> 6) >> 1, wn = (t >> 6) & 1;
    const int i15 = l & 15, g = l >> 4;

    f32x4 acc[4][4] = {};

    const int r0 = t >> 2;
    const int kc = ((t & 3) ^ ((t >> 3) & 3)) * 8;   // pre-swizzled k offset
    const size_t gA0 = (size_t)(oc0 + r0) * CC + kc;
    const size_t gA1 = (size_t)(oc0 + r0 + 64) * CC + kc;
    const size_t gB0 = (size_t)(n0 + r0) * CC + kc;
    const size_t gB1 = (size_t)(n0 + r0 + 64) * CC + kc;
    const int ldsOff = (t & 192) * 16;               // wave-uniform base

#define STAGE(buf, k0) do {                                                              \
    char* la_ = smem + (buf) * 16384 + ldsOff;                                           \
    char* lb_ = la_ + 8192;                                                              \
    __builtin_amdgcn_global_load_lds(                                                    \
        (const __attribute__((address_space(1))) void*)(wa + gA0 + (k0)),                \
        (__attribute__((address_space(3))) void*)la_, 16, 0, 0);                         \
    __builtin_amdgcn_global_load_lds(                                                    \
        (const __attribute__((address_space(1))) void*)(wa + gA1 + (k0)),                \
        (__attribute__((address_space(3))) void*)(la_ + 4096), 16, 0, 0);                \
    __builtin_amdgcn_global_load_lds(                                                    \
        (const __attribute__((address_space(1))) void*)(bt + gB0 + (k0)),                \
        (__attribute__((address_space(3))) void*)lb_, 16, 0, 0);                         \
    __builtin_amdgcn_global_load_lds(                                                    \
        (const __attribute__((address_space(1))) void*)(bt + gB1 + (k0)),                \
        (__attribute__((address_space(3))) void*)(lb_ + 4096), 16, 0, 0);                \
} while (0)

    const int colb = (g ^ ((i15 >> 1) & 3)) << 4;
    const int rbA = (wm * 64 + i15) * 64 + colb;     // + i*1024 per fragment
    const int rbB = (wn * 64 + i15) * 64 + colb;

    STAGE(0, 0);
    int cur = 0;
    for (int kt = 0; kt < 12; ++kt) {
        if (kt < 11) {
            STAGE(cur ^ 1, (kt + 1) * 32);
            asm volatile("s_waitcnt vmcnt(4)" ::: "memory");
        } else {
            asm volatile("s_waitcnt vmcnt(0)" ::: "memory");
        }
        __builtin_amdgcn_s_barrier();
        const char* bufA = smem + cur * 16384;
        const char* bufB = bufA + 8192;
        bf16x8 a[4], bb[4];
        #pragma unroll
        for (int i = 0; i < 4; ++i) {
            a[i]  = *(const bf16x8*)(bufA + rbA + i * 1024);
            bb[i] = *(const bf16x8*)(bufB + rbB + i * 1024);
        }
        #pragma unroll
        for (int mf = 0; mf < 4; ++mf)
            #pragma unroll
            for (int nf = 0; nf < 4; ++nf)
                acc[mf][nf] = __builtin_amdgcn_mfma_f32_16x16x32_bf16(a[mf], bb[nf], acc[mf][nf], 0, 0, 0);
        __builtin_amdgcn_sched_barrier(0);
        __builtin_amdgcn_s_barrier();
        cur ^= 1;
    }
#undef STAGE

    const int rl = (l >> 4) * 4;
    const int cl = l & 15;
    if (OUT_BF16) {
        ushort (* const sD)[136] = (ushort(*)[136])smem;
        #pragma unroll
        for (int mf = 0; mf < 4; ++mf) {
            const int ocl = wm * 64 + mf * 16 + rl;
            #pragma unroll
            for (int nf = 0; nf < 4; ++nf) {
                const int nl = wn * 64 + nf * 16 + cl;
                ushort4 w4;
                w4.x = f2b(acc[mf][nf][0] + bias[oc0 + ocl + 0]);
                w4.y = f2b(acc[mf][nf][1] + bias[oc0 + ocl + 1]);
                w4.z = f2b(acc[mf][nf][2] + bias[oc0 + ocl + 2]);
                w4.w = f2b(acc[mf][nf][3] + bias[oc0 + ocl + 3]);
                *(ushort4*)&sD[nl][ocl] = w4;
            }
        }
        __syncthreads();
        ushort* outp = (ushort*)outv;
        #pragma unroll
        for (int rr = 0; rr < 8; ++rr) {
            const int r = (t >> 4) + rr * 16;
            const int c8 = (t & 15) * 8;
            *(uint4*)&outp[(size_t)(n0 + r) * C3 + oc0 + c8] = *(const uint4*)&sD[r][c8];
        }
    } else {
        float* outp = (float*)outv;
        #pragma unroll
        for (int mf = 0; mf < 4; ++mf) {
            const int row = oc0 + wm * 64 + mf * 16 + rl;
            #pragma unroll
            for (int r = 0; r < 4; ++r) {
                const float bs = bias[row + r];
                #pragma unroll
                for (int nf = 0; nf < 4; ++nf) {
                    const int n = n0 + wn * 64 + nf * 16 + cl;
                    const int b = n / HWP, p = n - b * HWP;
                    outp[((size_t)b * OC + row + r) * HWP + p] = acc[mf][nf][r] + bs;
                }
            }
        }
    }
}

// ---------------------------------------------------------------------------
// MFMA windowed attention, P kept IN REGISTERS (no P LDS tile).
// qkv [n][1152] bf16 -> att [n][384] bf16.  One wave per (window, head).
// S^T = mfma(K,Q); in-register softmax; P packed to bf16-pair uints and
// redistributed to PV A-fragments via __shfl among lanes {l, l^16, l^32,
// l^48} (2 rounds: jt even/odd; derivation: U[u] = (u&1?phi:plo)
// [mt][2kt+(g>>1)] from lane (2(g&1)+(u>>1))*16+i15).  O bounces through
// the dead V tile for coalesced stores.  LDS: 21 KB (was 58 KB -> 21% occ).
// ---------------------------------------------------------------------------
__global__ __launch_bounds__(256) void attn_mfma(const ushort* __restrict__ qkv,
                                                 const float* __restrict__ pos,
                                                 ushort* __restrict__ out) {
    __shared__ float sPb[169];
    __shared__ __align__(16) ushort sV[4][64 * 40];   // per-wave V, then O bounce

    const int w = blockIdx.x, hg = blockIdx.y, b = blockIdx.z;
    const int wr = w >> 3, wc = w & 7;
    const int t = threadIdx.x, ww = t >> 6, l = t & 63;
    const int h = hg * 4 + ww;
    const int i15 = l & 15, g = l >> 4;
    const int hch = h * HD;
    if (t < 169) sPb[t] = pos[t];
    ushort* const sVw = sV[ww];

    // ---- stage V (rows 49..63 zeroed), chunk-XOR swizzle on d-chunks ----
    #pragma unroll
    for (int pass = 0; pass < 4; ++pass) {
        const int e = l + pass * 64;
        const int pix = e >> 2, c8 = e & 3;
        uint4 v = make_uint4(0, 0, 0, 0);
        if (pix < WSQ) {
            const int n = b * HWP + (wr * WSZ + pix / 7) * HH + wc * WSZ + pix % 7;
            v = *(const uint4*)&qkv[(size_t)n * C3 + 2 * CC + hch + c8 * 8];
        }
        const int cst = c8 ^ ((pix >> 2) & 3);
        *(uint4*)&sVw[pix * 40 + cst * 8] = v;
    }

    // ---- Q (B-frag) and K (A-frag) direct from global, zero-padded ----
    bf16x8 qf[4], kf[4];
    #pragma unroll
    for (int it = 0; it < 4; ++it) {
        const int i = it * 16 + i15;
        U128 uq, uk;
        uq.u = make_uint4(0, 0, 0, 0);
        uk.u = make_uint4(0, 0, 0, 0);
        if (i < WSQ) {
            const int n = b * HWP + (wr * WSZ + i / 7) * HH + wc * WSZ + i % 7;
            uq.u = *(const uint4*)&qkv[(size_t)n * C3 + hch + g * 8];
            uk.u = *(const uint4*)&qkv[(size_t)n * C3 + CC + hch + g * 8];
        }
        qf[it] = uq.v;
        kf[it] = uk.v;
    }

    // ---- S^T = K·Q^T : D[j][i], lane holds i = it*16+i15, j = jt*16+4g+r ----
    f32x4 sS[4][4] = {};
    #pragma unroll
    for (int jt = 0; jt < 4; ++jt)
        #pragma unroll
        for (int it = 0; it < 4; ++it)
            sS[jt][it] = __builtin_amdgcn_mfma_f32_16x16x32_bf16(kf[jt], qf[it], sS[jt][it], 0, 0, 0);

    __syncthreads();   // sPb ready (block-wide)

    // ---- fold scale + rel-pos bias + shift mask ----
    #pragma unroll
    for (int jt = 0; jt < 4; ++jt) {
        #pragma unroll
        for (int r = 0; r < 4; ++r) {
            const int j = jt * 16 + 4 * g + r;
            const bool jv = j < WSQ;
            const int pjr = j / 7, pjc = j % 7;
            #pragma unroll
            for (int it = 0; it < 4; ++it) {
                const int i = it * 16 + i15;
                float s = -1e30f;
                if ((i < WSQ) && jv) {
                    const int pir = i / 7, pic = i % 7;
                    s = sS[jt][it][r] * DKS + sPb[(pjr - pir + 6) * 13 + (pjc - pic + 6)];
                    if ((wr == 7 && ((pir >= 4) != (pjr >= 4))) ||
                        (wc == 7 && ((pic >= 4) != (pjc >= 4)))) s = -1e30f;
                }
                sS[jt][it][r] = s;
            }
        }
    }

    // ---- softmax over j per column i: 16 in-lane + lanes l^16, l^32 ----
    #pragma unroll
    for (int it = 0; it < 4; ++it) {
        float m = -1e30f;
        #pragma unroll
        for (int jt = 0; jt < 4; ++jt)
            #pragma unroll
            for (int r = 0; r < 4; ++r) m = fmaxf(m, sS[jt][it][r]);
        m = fmaxf(m, __shfl_xor(m, 16));
        m = fmaxf(m, __shfl_xor(m, 32));
        float sum = 0.f;
        #pragma unroll
        for (int jt = 0; jt < 4; ++jt)
            #pragma unroll
            for (int r = 0; r < 4; ++r) {
                const float e2 = __expf(sS[jt][it][r] - m);
                sS[jt][it][r] = e2;
                sum += e2;
            }
        sum += __shfl_xor(sum, 16);
        sum += __shfl_xor(sum, 32);
        const float inv = 1.f / sum;
        #pragma unroll
        for (int jt = 0; jt < 4; ++jt)
            #pragma unroll
            for (int r = 0; r < 4; ++r) sS[jt][it][r] *= inv;
    }

    // ---- pack P to bf16-pair uints in registers ----
    uint plo[4][4], phi[4][4];     // [it][jt]; covers j = jt*16+4g+{0,1}/{2,3}
    #pragma unroll
    for (int it = 0; it < 4; ++it)
        #pragma unroll
        for (int jt = 0; jt < 4; ++jt) {
            plo[it][jt] = (uint)f2b(sS[jt][it][0]) | ((uint)f2b(sS[jt][it][1]) << 16);
            phi[it][jt] = (uint)f2b(sS[jt][it][2]) | ((uint)f2b(sS[jt][it][3]) << 16);
        }

    // ---- PV with shfl-assembled A-fragments ----
    const int srcLo = (2 * (g & 1)) * 16 + i15;   // source lane for u>>1 == 0
    const int srcHi = srcLo + 16;                 // source lane for u>>1 == 1
    const bool oddHalf = ((g >> 1) & 1) != 0;

    f32x4 oacc[4][2] = {};
    #pragma unroll
    for (int kt = 0; kt < 2; ++kt) {
        bf16x8 bv[2];
        #pragma unroll
        for (int nt = 0; nt < 2; ++nt) {
            U128 u;
            #pragma unroll
            for (int s = 0; s < 8; ++s) {
                const int j = kt * 32 + 8 * g + s;
                const int d = nt * 16 + i15;
                const int cp = (d >> 3) ^ ((j >> 2) & 3);
                u.us[s] = sVw[j * 40 + cp * 8 + (d & 7)];
            }
            bv[nt] = u.v;
        }
        #pragma unroll
        for (int mt = 0; mt < 4; ++mt) {
            U128 pu;
            #pragma unroll
            for (int u2 = 0; u2 < 4; ++u2) {
                const int sl = (u2 >> 1) ? srcHi : srcLo;
                const uint vE = __shfl((u2 & 1) ? phi[mt][2 * kt]     : plo[mt][2 * kt],     sl, 64);
                const uint vO = __shfl((u2 & 1) ? phi[mt][2 * kt + 1] : plo[mt][2 * kt + 1], sl, 64);
                pu.ui[u2] = oddHalf ? vO : vE;
            }
            #pragma unroll
            for (int nt = 0; nt < 2; ++nt)
                oacc[mt][nt] = __builtin_amdgcn_mfma_f32_16x16x32_bf16(pu.v, bv[nt], oacc[mt][nt], 0, 0, 0);
        }
    }

    // ---- O bounce through sVw (V dead; pad 40, chunk-XOR by (i>>2)&3) ----
    #pragma unroll
    for (int mt = 0; mt < 4; ++mt)
        #pragma unroll
        for (int nt = 0; nt < 2; ++nt)
            #pragma unroll
            for (int r = 0; r < 4; ++r) {
                const int i = mt * 16 + 4 * g + r;
                const int d = nt * 16 + i15;
                const int cp = (d >> 3) ^ ((i >> 2) & 3);
                sVw[i * 40 + cp * 8 + (d & 7)] = f2b(oacc[mt][nt][r]);
            }

    // ---- coalesced readout ----
    #pragma unroll
    for (int pass = 0; pass < 4; ++pass) {
        const int e = l + pass * 64;
        const int pix = e >> 2, c8 = e & 3;
        if (pix < WSQ) {
            const int n = b * HWP + (wr * WSZ + pix / 7) * HH + wc * WSZ + pix % 7;
            const int cp = c8 ^ ((pix >> 2) & 3);
            *(uint4*)&out[(size_t)n * CC + hch + c8 * 8] = *(const uint4*)&sVw[pix * 40 + cp * 8];
        }
    }
}

// ---------------------------------------------------------------------------
extern "C" void kernel_launch(void* const* d_in, const int* in_sizes, int n_in,
                              void* d_out, int out_size, void* d_ws, size_t ws_size,
                              hipStream_t stream) {
    const float* x      = (const float*)d_in[0];
    const float* qkv_dw = (const float*)d_in[1];
    const float* qkv_pw = (const float*)d_in[2];
    const float* qkv_pb = (const float*)d_in[3];
    const float* out_dw = (const float*)d_in[4];
    const float* out_pw = (const float*)d_in[5];
    const float* out_pb = (const float*)d_in[6];
    const float* pos    = (const float*)d_in[7];

    // ws: A [NTOT][384] | B [NTOT][1152] | wA1 [1152][384] | wA2 [384][384]
    ushort* A   = (ushort*)d_ws;
    ushort* B   = A + (size_t)NTOT * CC;
    ushort* wA1 = B + (size_t)NTOT * C3;
    ushort* wA2 = wA1 + (size_t)C3 * CC;

    cvt_bf16<<<(C3 * CC + 255) / 256, 256, 0, stream>>>(qkv_pw, wA1, C3 * CC);
    cvt_bf16<<<(CC * CC + 255) / 256, 256, 0, stream>>>(out_pw, wA2, CC * CC);

    // 1) roll(-3) + depthwise -> A [n][384] bf16
    dconv_px<false><<<dim3(14, 12, BQ), 256, 0, stream>>>(x, qkv_dw, A, 3);
    // 2) pointwise 384->1152 -> B [n][1152] bf16  (oc-fastest grid)
    pconv_mfma<C3, true><<<dim3(C3 / 128, NTOT / 128), 256, 0, stream>>>(A, wA1, qkv_pb, B);
    // 3) windowed attention -> A [n][384] bf16
    attn_mfma<<<dim3(NWIN, NHEAD / 4, BQ), 256, 0, stream>>>(B, pos, A);
    // 4) roll(+3) + depthwise -> B (reused) [n][384] bf16
    dconv_px<true><<<dim3(14, 12, BQ), 256, 0, stream>>>(A, out_dw, B, 53);
    // 5) pointwise 384->384 -> d_out fp32 NCHW  (oc-fastest grid)
    pconv_mfma<CC, false><<<dim3(CC / 128, NTOT / 128), 256, 0, stream>>>(B, wA2, out_pb, (float*)d_out);
}

// Round 15
// 207.169 us; speedup vs baseline: 5.9717x; 1.2672x over previous
//
#include <hip/hip_runtime.h>
#include <hip/hip_bf16.h>
#include <cstddef>
#include <cstdint>

#define BQ    16
#define CC    384
#define C3    1152
#define HH    56
#define HWP   3136
#define NTOT  (BQ * HWP)   // 50176
#define NHEAD 12
#define HD    32
#define WSZ   7
#define NWIN  64
#define WSQ   49
#define DKS   0.17677669529663687f

typedef __attribute__((ext_vector_type(8))) short bf16x8;
typedef __attribute__((ext_vector_type(4))) float f32x4;

union U128 { uint4 u; bf16x8 v; ushort us[8]; uint ui[4]; };

__device__ __forceinline__ ushort f2b(float f) {
    __hip_bfloat16 h = __float2bfloat16(f);
    return *reinterpret_cast<ushort*>(&h);
}
__device__ __forceinline__ float b2f(ushort u) {
    __hip_bfloat16 h;
    *reinterpret_cast<ushort*>(&h) = u;
    return __bfloat162float(h);
}

__global__ void cvt_bf16(const float* __restrict__ in, ushort* __restrict__ out, int n) {
    const int i = blockIdx.x * 256 + threadIdx.x;
    if (i < n) out[i] = f2b(in[i]);
}

// ---------------------------------------------------------------------------
// roll + depthwise 3x3, pixel-major output [n][384].
// LDS pl[6][32][68] holds SOURCE-coordinate columns (0..55) + wrap replica
// (56..61); the column roll is a compile-time read offset (S template arg,
// odd -> sc0 even -> contiguous 6-ushort reads merge to b32/b64).  Image-edge
// padding = two v[k]=0 fixups.  fp32 staging: aligned float4 + ushort4 LDS
// writes.  Stride 68 ushorts = 136 B = 34 banks -> 2-way (free).
// Grid (14 bands, 12 cgroups, 16 b).  S: 3 (dconv1) or 53 (== -3, dconv2).
// ---------------------------------------------------------------------------
template <bool BF16IN, int S>
__global__ __launch_bounds__(256) void dconv_px(const void* __restrict__ inv,
                                                const float* __restrict__ dw,
                                                ushort* __restrict__ out) {
    __shared__ ushort pl[6][32][68];
    const int band = blockIdx.x, cg = blockIdx.y, b = blockIdx.z;
    const int i0 = band * 4;
    const int t = threadIdx.x;
    const int ch = t & 31;

    float wreg[9];
    #pragma unroll
    for (int k = 0; k < 9; ++k) wreg[k] = dw[(cg * 32 + ch) * 9 + k];

    if (BF16IN) {
        // input bf16 [n][384]: thread owns (c8 = t&3, sc = t>>2 in 0..63);
        // cc = sc%56 (cols 56.. are the wrap replica); walks 6 rows.
        const ushort* src = (const ushort*)inv;
        const int c8 = t & 3, sc = t >> 2;
        const int cc = sc < 56 ? sc : sc - 56;
        #pragma unroll
        for (int lr = 0; lr < 6; ++lr) {
            const int gi = i0 + lr - 1;
            U128 u; u.u = make_uint4(0, 0, 0, 0);
            if (gi >= 0 && gi < HH) {
                int rr = gi + S; if (rr >= HH) rr -= HH;
                u.u = *(const uint4*)&src[(size_t)(b * HWP + rr * HH + cc) * CC + cg * 32 + c8 * 8];
            }
            #pragma unroll
            for (int k2 = 0; k2 < 8; ++k2) pl[lr][c8 * 8 + k2][sc] = u.us[k2];
        }
    } else {
        // input fp32 [b][384][56][56]: thread owns (cq = t&15 col-quad, q0 =
        // t>>4); 12 iters of aligned float4 + ushort4 LDS write.  Quads >=14
        // produce the wrap replica (scb = cq*4 - 56).
        const float* src = (const float*)inv;
        const int cq = t & 15, q0 = t >> 4;
        const int scb = cq < 14 ? cq * 4 : cq * 4 - 56;
        #pragma unroll
        for (int k = 0; k < 12; ++k) {
            const int pair = q0 + k * 16;          // 0..191
            const int lc = pair & 31, lr = pair >> 5;
            const int gi = i0 + lr - 1;
            float4 v = make_float4(0.f, 0.f, 0.f, 0.f);
            if (gi >= 0 && gi < HH) {
                int rr = gi + S; if (rr >= HH) rr -= HH;
                v = *(const float4*)&src[((size_t)(b * CC + cg * 32 + lc)) * HWP + rr * HH + scb];
            }
            ushort4 w;
            w.x = f2b(v.x); w.y = f2b(v.y); w.z = f2b(v.z); w.w = f2b(v.w);
            *(ushort4*)&pl[lr][lc][cq * 4] = w;
        }
    }
    __syncthreads();

    // compute: 56 units = 14 colblocks x 4 rows; unit = iter*8 + (t>>5).
    const int u = t >> 5;
    #pragma unroll
    for (int iter = 0; iter < 7; ++iter) {
        const int unit = iter * 8 + u;
        const int colb = unit >> 2;
        const int row  = unit & 3;
        const int c0 = colb * 4;
        int sc0 = c0 - 1 + S; if (sc0 >= HH) sc0 -= HH;   // even (S odd, c0 even)
        float acc[4] = {0.f, 0.f, 0.f, 0.f};
        #pragma unroll
        for (int di = 0; di < 3; ++di) {
            const ushort* rp = &pl[row + di][ch][0];
            float v[6];
            #pragma unroll
            for (int k = 0; k < 6; ++k) v[k] = b2f(rp[sc0 + k]);
            if (colb == 0)  v[0] = 0.f;   // image col -1 pad
            if (colb == 13) v[5] = 0.f;   // image col 56 pad
            #pragma unroll
            for (int cc2 = 0; cc2 < 4; ++cc2) {
                acc[cc2] += wreg[di * 3 + 0] * v[cc2];
                acc[cc2] += wreg[di * 3 + 1] * v[cc2 + 1];
                acc[cc2] += wreg[di * 3 + 2] * v[cc2 + 2];
            }
        }
        const int orow = i0 + row;
        #pragma unroll
        for (int cc2 = 0; cc2 < 4; ++cc2)
            out[(size_t)(b * HWP + orow * HH + c0 + cc2) * CC + cg * 32 + ch] = f2b(acc[cc2]);
    }
}

// ---------------------------------------------------------------------------
// MFMA GEMM.  r11 structure (2-phase dbuf, counted vmcnt, XOR swizzle,
// oc-fastest) + bijective XCD-chunk swizzle: each XCD's L2 owns a contiguous
// logical range, so the OC/128 blocks sharing an activation panel land on
// ONE XCD (r13 FETCH was 164 MB vs ~40 ideal from cross-XCD re-fetch).
// 1-D grid, nwg % 8 == 0 (3528 / 1176).
// ---------------------------------------------------------------------------
template <int OC, bool OUT_BF16>
__global__ __launch_bounds__(256) void pconv_mfma(const ushort* __restrict__ bt,
                                                  const ushort* __restrict__ wa,
                                                  const float* __restrict__ bias,
                                                  void* __restrict__ outv) {
    __shared__ __align__(16) char smem[OUT_BF16 ? 34816 : 32768];

    const int nwg = gridDim.x;
    const int cpx = nwg >> 3;
    const int id  = blockIdx.x;
    const int wg  = (id & 7) * cpx + (id >> 3);
    const int oc0 = (wg % (OC / 128)) * 128;
    const int n0  = (wg / (OC / 128)) * 128;

    const int t   = threadIdx.x;
    const int l   = t & 63;
    const int wm  = (t >> 6) >> 1, wn = (t >> 6) & 1;
    const int i15 = l & 15, g = l >> 4;

    f32x4 acc[4][4] = {};

    const int r0 = t >> 2;
    const int kc = ((t & 3) ^ ((t >> 3) & 3)) * 8;   // pre-swizzled k offset
    const size_t gA0 = (size_t)(oc0 + r0) * CC + kc;
    const size_t gA1 = (size_t)(oc0 + r0 + 64) * CC + kc;
    const size_t gB0 = (size_t)(n0 + r0) * CC + kc;
    const size_t gB1 = (size_t)(n0 + r0 + 64) * CC + kc;
    const int ldsOff = (t & 192) * 16;               // wave-uniform base

#define STAGE(buf, k0) do {                                                              \
    char* la_ = smem + (buf) * 16384 + ldsOff;                                           \
    char* lb_ = la_ + 8192;                                                              \
    __builtin_amdgcn_global_load_lds(                                                    \
        (const __attribute__((address_space(1))) void*)(wa + gA0 + (k0)),                \
        (__attribute__((address_space(3))) void*)la_, 16, 0, 0);                         \
    __builtin_amdgcn_global_load_lds(                                                    \
        (const __attribute__((address_space(1))) void*)(wa + gA1 + (k0)),                \
        (__attribute__((address_space(3))) void*)(la_ + 4096), 16, 0, 0);                \
    __builtin_amdgcn_global_load_lds(                                                    \
        (const __attribute__((address_space(1))) void*)(bt + gB0 + (k0)),                \
        (__attribute__((address_space(3))) void*)lb_, 16, 0, 0);                         \
    __builtin_amdgcn_global_load_lds(                                                    \
        (const __attribute__((address_space(1))) void*)(bt + gB1 + (k0)),                \
        (__attribute__((address_space(3))) void*)(lb_ + 4096), 16, 0, 0);                \
} while (0)

    const int colb = (g ^ ((i15 >> 1) & 3)) << 4;
    const int rbA = (wm * 64 + i15) * 64 + colb;     // + i*1024 per fragment
    const int rbB = (wn * 64 + i15) * 64 + colb;

    STAGE(0, 0);
    int cur = 0;
    for (int kt = 0; kt < 12; ++kt) {
        if (kt < 11) {
            STAGE(cur ^ 1, (kt + 1) * 32);
            asm volatile("s_waitcnt vmcnt(4)" ::: "memory");
        } else {
            asm volatile("s_waitcnt vmcnt(0)" ::: "memory");
        }
        __builtin_amdgcn_s_barrier();
        const char* bufA = smem + cur * 16384;
        const char* bufB = bufA + 8192;
        bf16x8 a[4], bb[4];
        #pragma unroll
        for (int i = 0; i < 4; ++i) {
            a[i]  = *(const bf16x8*)(bufA + rbA + i * 1024);
            bb[i] = *(const bf16x8*)(bufB + rbB + i * 1024);
        }
        #pragma unroll
        for (int mf = 0; mf < 4; ++mf)
            #pragma unroll
            for (int nf = 0; nf < 4; ++nf)
                acc[mf][nf] = __builtin_amdgcn_mfma_f32_16x16x32_bf16(a[mf], bb[nf], acc[mf][nf], 0, 0, 0);
        __builtin_amdgcn_sched_barrier(0);
        __builtin_amdgcn_s_barrier();
        cur ^= 1;
    }
#undef STAGE

    const int rl = (l >> 4) * 4;
    const int cl = l & 15;
    if (OUT_BF16) {
        ushort (* const sD)[136] = (ushort(*)[136])smem;
        #pragma unroll
        for (int mf = 0; mf < 4; ++mf) {
            const int ocl = wm * 64 + mf * 16 + rl;
            #pragma unroll
            for (int nf = 0; nf < 4; ++nf) {
                const int nl = wn * 64 + nf * 16 + cl;
                ushort4 w4;
                w4.x = f2b(acc[mf][nf][0] + bias[oc0 + ocl + 0]);
                w4.y = f2b(acc[mf][nf][1] + bias[oc0 + ocl + 1]);
                w4.z = f2b(acc[mf][nf][2] + bias[oc0 + ocl + 2]);
                w4.w = f2b(acc[mf][nf][3] + bias[oc0 + ocl + 3]);
                *(ushort4*)&sD[nl][ocl] = w4;
            }
        }
        __syncthreads();
        ushort* outp = (ushort*)outv;
        #pragma unroll
        for (int rr = 0; rr < 8; ++rr) {
            const int r = (t >> 4) + rr * 16;
            const int c8 = (t & 15) * 8;
            *(uint4*)&outp[(size_t)(n0 + r) * C3 + oc0 + c8] = *(const uint4*)&sD[r][c8];
        }
    } else {
        float* outp = (float*)outv;
        #pragma unroll
        for (int mf = 0; mf < 4; ++mf) {
            const int row = oc0 + wm * 64 + mf * 16 + rl;
            #pragma unroll
            for (int r = 0; r < 4; ++r) {
                const float bs = bias[row + r];
                #pragma unroll
                for (int nf = 0; nf < 4; ++nf) {
                    const int n = n0 + wn * 64 + nf * 16 + cl;
                    const int b = n / HWP, p = n - b * HWP;
                    outp[((size_t)b * OC + row + r) * HWP + p] = acc[mf][nf][r] + bs;
                }
            }
        }
    }
}

// ---------------------------------------------------------------------------
// MFMA windowed attention, P in registers.  (unchanged from r13)
// ---------------------------------------------------------------------------
__global__ __launch_bounds__(256) void attn_mfma(const ushort* __restrict__ qkv,
                                                 const float* __restrict__ pos,
                                                 ushort* __restrict__ out) {
    __shared__ float sPb[169];
    __shared__ __align__(16) ushort sV[4][64 * 40];   // per-wave V, then O bounce

    const int w = blockIdx.x, hg = blockIdx.y, b = blockIdx.z;
    const int wr = w >> 3, wc = w & 7;
    const int t = threadIdx.x, ww = t >> 6, l = t & 63;
    const int h = hg * 4 + ww;
    const int i15 = l & 15, g = l >> 4;
    const int hch = h * HD;
    if (t < 169) sPb[t] = pos[t];
    ushort* const sVw = sV[ww];

    #pragma unroll
    for (int pass = 0; pass < 4; ++pass) {
        const int e = l + pass * 64;
        const int pix = e >> 2, c8 = e & 3;
        uint4 v = make_uint4(0, 0, 0, 0);
        if (pix < WSQ) {
            const int n = b * HWP + (wr * WSZ + pix / 7) * HH + wc * WSZ + pix % 7;
            v = *(const uint4*)&qkv[(size_t)n * C3 + 2 * CC + hch + c8 * 8];
        }
        const int cst = c8 ^ ((pix >> 2) & 3);
        *(uint4*)&sVw[pix * 40 + cst * 8] = v;
    }

    bf16x8 qf[4], kf[4];
    #pragma unroll
    for (int it = 0; it < 4; ++it) {
        const int i = it * 16 + i15;
        U128 uq, uk;
        uq.u = make_uint4(0, 0, 0, 0);
        uk.u = make_uint4(0, 0, 0, 0);
        if (i < WSQ) {
            const int n = b * HWP + (wr * WSZ + i / 7) * HH + wc * WSZ + i % 7;
            uq.u = *(const uint4*)&qkv[(size_t)n * C3 + hch + g * 8];
            uk.u = *(const uint4*)&qkv[(size_t)n * C3 + CC + hch + g * 8];
        }
        qf[it] = uq.v;
        kf[it] = uk.v;
    }

    f32x4 sS[4][4] = {};
    #pragma unroll
    for (int jt = 0; jt < 4; ++jt)
        #pragma unroll
        for (int it = 0; it < 4; ++it)
            sS[jt][it] = __builtin_amdgcn_mfma_f32_16x16x32_bf16(kf[jt], qf[it], sS[jt][it], 0, 0, 0);

    __syncthreads();   // sPb ready (block-wide)

    #pragma unroll
    for (int jt = 0; jt < 4; ++jt) {
        #pragma unroll
        for (int r = 0; r < 4; ++r) {
            const int j = jt * 16 + 4 * g + r;
            const bool jv = j < WSQ;
            const int pjr = j / 7, pjc = j % 7;
            #pragma unroll
            for (int it = 0; it < 4; ++it) {
                const int i = it * 16 + i15;
                float s = -1e30f;
                if ((i < WSQ) && jv) {
                    const int pir = i / 7, pic = i % 7;
                    s = sS[jt][it][r] * DKS + sPb[(pjr - pir + 6) * 13 + (pjc - pic + 6)];
                    if ((wr == 7 && ((pir >= 4) != (pjr >= 4))) ||
                        (wc == 7 && ((pic >= 4) != (pjc >= 4)))) s = -1e30f;
                }
                sS[jt][it][r] = s;
            }
        }
    }

    #pragma unroll
    for (int it = 0; it < 4; ++it) {
        float m = -1e30f;
        #pragma unroll
        for (int jt = 0; jt < 4; ++jt)
            #pragma unroll
            for (int r = 0; r < 4; ++r) m = fmaxf(m, sS[jt][it][r]);
        m = fmaxf(m, __shfl_xor(m, 16));
        m = fmaxf(m, __shfl_xor(m, 32));
        float sum = 0.f;
        #pragma unroll
        for (int jt = 0; jt < 4; ++jt)
            #pragma unroll
            for (int r = 0; r < 4; ++r) {
                const float e2 = __expf(sS[jt][it][r] - m);
                sS[jt][it][r] = e2;
                sum += e2;
            }
        sum += __shfl_xor(sum, 16);
        sum += __shfl_xor(sum, 32);
        const float inv = 1.f / sum;
        #pragma unroll
        for (int jt = 0; jt < 4; ++jt)
            #pragma unroll
            for (int r = 0; r < 4; ++r) sS[jt][it][r] *= inv;
    }

    uint plo[4][4], phi[4][4];     // [it][jt]; covers j = jt*16+4g+{0,1}/{2,3}
    #pragma unroll
    for (int it = 0; it < 4; ++it)
        #pragma unroll
        for (int jt = 0; jt < 4; ++jt) {
            plo[it][jt] = (uint)f2b(sS[jt][it][0]) | ((uint)f2b(sS[jt][it][1]) << 16);
            phi[it][jt] = (uint)f2b(sS[jt][it][2]) | ((uint)f2b(sS[jt][it][3]) << 16);
        }

    const int srcLo = (2 * (g & 1)) * 16 + i15;   // source lane for u>>1 == 0
    const int srcHi = srcLo + 16;                 // source lane for u>>1 == 1
    const bool oddHalf = ((g >> 1) & 1) != 0;

    f32x4 oacc[4][2] = {};
    #pragma unroll
    for (int kt = 0; kt < 2; ++kt) {
        bf16x8 bv[2];
        #pragma unroll
        for (int nt = 0; nt < 2; ++nt) {
            U128 u;
            #pragma unroll
            for (int s = 0; s < 8; ++s) {
                const int j = kt * 32 + 8 * g + s;
                const int d = nt * 16 + i15;
                const int cp = (d >> 3) ^ ((j >> 2) & 3);
                u.us[s] = sVw[j * 40 + cp * 8 + (d & 7)];
            }
            bv[nt] = u.v;
        }
        #pragma unroll
        for (int mt = 0; mt < 4; ++mt) {
            U128 pu;
            #pragma unroll
            for (int u2 = 0; u2 < 4; ++u2) {
                const int sl = (u2 >> 1) ? srcHi : srcLo;
                const uint vE = __shfl((u2 & 1) ? phi[mt][2 * kt]     : plo[mt][2 * kt],     sl, 64);
                const uint vO = __shfl((u2 & 1) ? phi[mt][2 * kt + 1] : plo[mt][2 * kt + 1], sl, 64);
                pu.ui[u2] = oddHalf ? vO : vE;
            }
            #pragma unroll
            for (int nt = 0; nt < 2; ++nt)
                oacc[mt][nt] = __builtin_amdgcn_mfma_f32_16x16x32_bf16(pu.v, bv[nt], oacc[mt][nt], 0, 0, 0);
        }
    }

    #pragma unroll
    for (int mt = 0; mt < 4; ++mt)
        #pragma unroll
        for (int nt = 0; nt < 2; ++nt)
            #pragma unroll
            for (int r = 0; r < 4; ++r) {
                const int i = mt * 16 + 4 * g + r;
                const int d = nt * 16 + i15;
                const int cp = (d >> 3) ^ ((i >> 2) & 3);
                sVw[i * 40 + cp * 8 + (d & 7)] = f2b(oacc[mt][nt][r]);
            }

    #pragma unroll
    for (int pass = 0; pass < 4; ++pass) {
        const int e = l + pass * 64;
        const int pix = e >> 2, c8 = e & 3;
        if (pix < WSQ) {
            const int n = b * HWP + (wr * WSZ + pix / 7) * HH + wc * WSZ + pix % 7;
            const int cp = c8 ^ ((pix >> 2) & 3);
            *(uint4*)&out[(size_t)n * CC + hch + c8 * 8] = *(const uint4*)&sVw[pix * 40 + cp * 8];
        }
    }
}

// ---------------------------------------------------------------------------
extern "C" void kernel_launch(void* const* d_in, const int* in_sizes, int n_in,
                              void* d_out, int out_size, void* d_ws, size_t ws_size,
                              hipStream_t stream) {
    const float* x      = (const float*)d_in[0];
    const float* qkv_dw = (const float*)d_in[1];
    const float* qkv_pw = (const float*)d_in[2];
    const float* qkv_pb = (const float*)d_in[3];
    const float* out_dw = (const float*)d_in[4];
    const float* out_pw = (const float*)d_in[5];
    const float* out_pb = (const float*)d_in[6];
    const float* pos    = (const float*)d_in[7];

    // ws: A [NTOT][384] | B [NTOT][1152] | wA1 [1152][384] | wA2 [384][384]
    ushort* A   = (ushort*)d_ws;
    ushort* B   = A + (size_t)NTOT * CC;
    ushort* wA1 = B + (size_t)NTOT * C3;
    ushort* wA2 = wA1 + (size_t)C3 * CC;

    cvt_bf16<<<(C3 * CC + 255) / 256, 256, 0, stream>>>(qkv_pw, wA1, C3 * CC);
    cvt_bf16<<<(CC * CC + 255) / 256, 256, 0, stream>>>(out_pw, wA2, CC * CC);

    // 1) roll(-3) + depthwise -> A [n][384] bf16
    dconv_px<false, 3><<<dim3(14, 12, BQ), 256, 0, stream>>>(x, qkv_dw, A);
    // 2) pointwise 384->1152 -> B [n][1152] bf16  (XCD-swizzled 1-D grid)
    pconv_mfma<C3, true><<<dim3((C3 / 128) * (NTOT / 128)), 256, 0, stream>>>(A, wA1, qkv_pb, B);
    // 3) windowed attention -> A [n][384] bf16
    attn_mfma<<<dim3(NWIN, NHEAD / 4, BQ), 256, 0, stream>>>(B, pos, A);
    // 4) roll(+3) + depthwise -> B (reused) [n][384] bf16
    dconv_px<true, 53><<<dim3(14, 12, BQ), 256, 0, stream>>>(A, out_dw, B);
    // 5) pointwise 384->384 -> d_out fp32 NCHW  (XCD-swizzled 1-D grid)
    pconv_mfma<CC, false><<<dim3((CC / 128) * (NTOT / 128)), 256, 0, stream>>>(B, wA2, out_pb, (float*)d_out);
}

// Round 16
// 198.166 us; speedup vs baseline: 6.2430x; 1.0454x over previous
//
#include <hip/hip_runtime.h>
#include <hip/hip_bf16.h>
#include <cstddef>
#include <cstdint>

#define BQ    16
#define CC    384
#define C3    1152
#define HH    56
#define HWP   3136
#define NTOT  (BQ * HWP)   // 50176
#define NHEAD 12
#define HD    32
#define WSZ   7
#define NWIN  64
#define WSQ   49
#define DKS   0.17677669529663687f

typedef __attribute__((ext_vector_type(8))) short bf16x8;
typedef __attribute__((ext_vector_type(4))) float f32x4;

union U128 { uint4 u; bf16x8 v; ushort us[8]; uint ui[4]; };

__device__ __forceinline__ ushort f2b(float f) {
    __hip_bfloat16 h = __float2bfloat16(f);
    return *reinterpret_cast<ushort*>(&h);
}
__device__ __forceinline__ float b2f(ushort u) {
    __hip_bfloat16 h;
    *reinterpret_cast<ushort*>(&h) = u;
    return __bfloat162float(h);
}

__global__ void cvt_bf16(const float* __restrict__ in, ushort* __restrict__ out, int n) {
    const int i = blockIdx.x * 256 + threadIdx.x;
    if (i < n) out[i] = f2b(in[i]);
}

// ---------------------------------------------------------------------------
// Precompute the additive fold matrix M[4][64][64] (f32):
//   M[v][j][i] = (i<49 && j<49 && !masked(v,i,j)) ? bias(i,j) : -1e30
// v = (wr==7)*2 + (wc==7).  Window-independent; L1-resident in attn.
// ---------------------------------------------------------------------------
__global__ void prep_mask(const float* __restrict__ pos, float* __restrict__ M) {
    const int idx = blockIdx.x * 256 + threadIdx.x;   // 4*64*64 = 16384
    const int v = idx >> 12, rem = idx & 4095;
    const int j = rem >> 6, i = rem & 63;
    float m = -1e30f;
    if (i < WSQ && j < WSQ) {
        const int pir = i / WSZ, pic = i - pir * WSZ;
        const int pjr = j / WSZ, pjc = j - pjr * WSZ;
        const bool msk = ((v & 2) && ((pir >= 4) != (pjr >= 4))) ||
                         ((v & 1) && ((pic >= 4) != (pjc >= 4)));
        m = msk ? -1e30f : pos[(pjr - pir + 6) * 13 + (pjc - pic + 6)];
    }
    M[idx] = m;
}

// ---------------------------------------------------------------------------
// roll + depthwise 3x3, pixel-major output [n][384].  (unchanged from r15)
// ---------------------------------------------------------------------------
template <bool BF16IN, int S>
__global__ __launch_bounds__(256) void dconv_px(const void* __restrict__ inv,
                                                const float* __restrict__ dw,
                                                ushort* __restrict__ out) {
    __shared__ ushort pl[6][32][68];
    const int band = blockIdx.x, cg = blockIdx.y, b = blockIdx.z;
    const int i0 = band * 4;
    const int t = threadIdx.x;
    const int ch = t & 31;

    float wreg[9];
    #pragma unroll
    for (int k = 0; k < 9; ++k) wreg[k] = dw[(cg * 32 + ch) * 9 + k];

    if (BF16IN) {
        const ushort* src = (const ushort*)inv;
        const int c8 = t & 3, sc = t >> 2;
        const int cc = sc < 56 ? sc : sc - 56;
        #pragma unroll
        for (int lr = 0; lr < 6; ++lr) {
            const int gi = i0 + lr - 1;
            U128 u; u.u = make_uint4(0, 0, 0, 0);
            if (gi >= 0 && gi < HH) {
                int rr = gi + S; if (rr >= HH) rr -= HH;
                u.u = *(const uint4*)&src[(size_t)(b * HWP + rr * HH + cc) * CC + cg * 32 + c8 * 8];
            }
            #pragma unroll
            for (int k2 = 0; k2 < 8; ++k2) pl[lr][c8 * 8 + k2][sc] = u.us[k2];
        }
    } else {
        const float* src = (const float*)inv;
        const int cq = t & 15, q0 = t >> 4;
        const int scb = cq < 14 ? cq * 4 : cq * 4 - 56;
        #pragma unroll
        for (int k = 0; k < 12; ++k) {
            const int pair = q0 + k * 16;          // 0..191
            const int lc = pair & 31, lr = pair >> 5;
            const int gi = i0 + lr - 1;
            float4 v = make_float4(0.f, 0.f, 0.f, 0.f);
            if (gi >= 0 && gi < HH) {
                int rr = gi + S; if (rr >= HH) rr -= HH;
                v = *(const float4*)&src[((size_t)(b * CC + cg * 32 + lc)) * HWP + rr * HH + scb];
            }
            ushort4 w;
            w.x = f2b(v.x); w.y = f2b(v.y); w.z = f2b(v.z); w.w = f2b(v.w);
            *(ushort4*)&pl[lr][lc][cq * 4] = w;
        }
    }
    __syncthreads();

    const int u = t >> 5;
    #pragma unroll
    for (int iter = 0; iter < 7; ++iter) {
        const int unit = iter * 8 + u;
        const int colb = unit >> 2;
        const int row  = unit & 3;
        const int c0 = colb * 4;
        int sc0 = c0 - 1 + S; if (sc0 >= HH) sc0 -= HH;   // even (S odd, c0 even)
        float acc[4] = {0.f, 0.f, 0.f, 0.f};
        #pragma unroll
        for (int di = 0; di < 3; ++di) {
            const ushort* rp = &pl[row + di][ch][0];
            float v[6];
            #pragma unroll
            for (int k = 0; k < 6; ++k) v[k] = b2f(rp[sc0 + k]);
            if (colb == 0)  v[0] = 0.f;   // image col -1 pad
            if (colb == 13) v[5] = 0.f;   // image col 56 pad
            #pragma unroll
            for (int cc2 = 0; cc2 < 4; ++cc2) {
                acc[cc2] += wreg[di * 3 + 0] * v[cc2];
                acc[cc2] += wreg[di * 3 + 1] * v[cc2 + 1];
                acc[cc2] += wreg[di * 3 + 2] * v[cc2 + 2];
            }
        }
        const int orow = i0 + row;
        #pragma unroll
        for (int cc2 = 0; cc2 < 4; ++cc2)
            out[(size_t)(b * HWP + orow * HH + c0 + cc2) * CC + cg * 32 + ch] = f2b(acc[cc2]);
    }
}

// ---------------------------------------------------------------------------
// MFMA GEMM.  (unchanged from r15: 2-phase dbuf, counted vmcnt, XOR swizzle,
// XCD-chunk-swizzled 1-D grid)
// ---------------------------------------------------------------------------
template <int OC, bool OUT_BF16>
__global__ __launch_bounds__(256) void pconv_mfma(const ushort* __restrict__ bt,
                                                  const ushort* __restrict__ wa,
                                                  const float* __restrict__ bias,
                                                  void* __restrict__ outv) {
    __shared__ __align__(16) char smem[OUT_BF16 ? 34816 : 32768];

    const int nwg = gridDim.x;
    const int cpx = nwg >> 3;
    const int id  = blockIdx.x;
    const int wg  = (id & 7) * cpx + (id >> 3);
    const int oc0 = (wg % (OC / 128)) * 128;
    const int n0  = (wg / (OC / 128)) * 128;

    const int t   = threadIdx.x;
    const int l   = t & 63;
    const int wm  = (t >> 6) >> 1, wn = (t >> 6) & 1;
    const int i15 = l & 15, g = l >> 4;

    f32x4 acc[4][4] = {};

    const int r0 = t >> 2;
    const int kc = ((t & 3) ^ ((t >> 3) & 3)) * 8;   // pre-swizzled k offset
    const size_t gA0 = (size_t)(oc0 + r0) * CC + kc;
    const size_t gA1 = (size_t)(oc0 + r0 + 64) * CC + kc;
    const size_t gB0 = (size_t)(n0 + r0) * CC + kc;
    const size_t gB1 = (size_t)(n0 + r0 + 64) * CC + kc;
    const int ldsOff = (t & 192) * 16;               // wave-uniform base

#define STAGE(buf, k0) do {                                                              \
    char* la_ = smem + (buf) * 16384 + ldsOff;                                           \
    char* lb_ = la_ + 8192;                                                              \
    __builtin_amdgcn_global_load_lds(                                                    \
        (const __attribute__((address_space(1))) void*)(wa + gA0 + (k0)),                \
        (__attribute__((address_space(3))) void*)la_, 16, 0, 0);                         \
    __builtin_amdgcn_global_load_lds(                                                    \
        (const __attribute__((address_space(1))) void*)(wa + gA1 + (k0)),                \
        (__attribute__((address_space(3))) void*)(la_ + 4096), 16, 0, 0);                \
    __builtin_amdgcn_global_load_lds(                                                    \
        (const __attribute__((address_space(1))) void*)(bt + gB0 + (k0)),                \
        (__attribute__((address_space(3))) void*)lb_, 16, 0, 0);                         \
    __builtin_amdgcn_global_load_lds(                                                    \
        (const __attribute__((address_space(1))) void*)(bt + gB1 + (k0)),                \
        (__attribute__((address_space(3))) void*)(lb_ + 4096), 16, 0, 0);                \
} while (0)

    const int colb = (g ^ ((i15 >> 1) & 3)) << 4;
    const int rbA = (wm * 64 + i15) * 64 + colb;     // + i*1024 per fragment
    const int rbB = (wn * 64 + i15) * 64 + colb;

    STAGE(0, 0);
    int cur = 0;
    for (int kt = 0; kt < 12; ++kt) {
        if (kt < 11) {
            STAGE(cur ^ 1, (kt + 1) * 32);
            asm volatile("s_waitcnt vmcnt(4)" ::: "memory");
        } else {
            asm volatile("s_waitcnt vmcnt(0)" ::: "memory");
        }
        __builtin_amdgcn_s_barrier();
        const char* bufA = smem + cur * 16384;
        const char* bufB = bufA + 8192;
        bf16x8 a[4], bb[4];
        #pragma unroll
        for (int i = 0; i < 4; ++i) {
            a[i]  = *(const bf16x8*)(bufA + rbA + i * 1024);
            bb[i] = *(const bf16x8*)(bufB + rbB + i * 1024);
        }
        #pragma unroll
        for (int mf = 0; mf < 4; ++mf)
            #pragma unroll
            for (int nf = 0; nf < 4; ++nf)
                acc[mf][nf] = __builtin_amdgcn_mfma_f32_16x16x32_bf16(a[mf], bb[nf], acc[mf][nf], 0, 0, 0);
        __builtin_amdgcn_sched_barrier(0);
        __builtin_amdgcn_s_barrier();
        cur ^= 1;
    }
#undef STAGE

    const int rl = (l >> 4) * 4;
    const int cl = l & 15;
    if (OUT_BF16) {
        ushort (* const sD)[136] = (ushort(*)[136])smem;
        #pragma unroll
        for (int mf = 0; mf < 4; ++mf) {
            const int ocl = wm * 64 + mf * 16 + rl;
            #pragma unroll
            for (int nf = 0; nf < 4; ++nf) {
                const int nl = wn * 64 + nf * 16 + cl;
                ushort4 w4;
                w4.x = f2b(acc[mf][nf][0] + bias[oc0 + ocl + 0]);
                w4.y = f2b(acc[mf][nf][1] + bias[oc0 + ocl + 1]);
                w4.z = f2b(acc[mf][nf][2] + bias[oc0 + ocl + 2]);
                w4.w = f2b(acc[mf][nf][3] + bias[oc0 + ocl + 3]);
                *(ushort4*)&sD[nl][ocl] = w4;
            }
        }
        __syncthreads();
        ushort* outp = (ushort*)outv;
        #pragma unroll
        for (int rr = 0; rr < 8; ++rr) {
            const int r = (t >> 4) + rr * 16;
            const int c8 = (t & 15) * 8;
            *(uint4*)&outp[(size_t)(n0 + r) * C3 + oc0 + c8] = *(const uint4*)&sD[r][c8];
        }
    } else {
        float* outp = (float*)outv;
        #pragma unroll
        for (int mf = 0; mf < 4; ++mf) {
            const int row = oc0 + wm * 64 + mf * 16 + rl;
            #pragma unroll
            for (int r = 0; r < 4; ++r) {
                const float bs = bias[row + r];
                #pragma unroll
                for (int nf = 0; nf < 4; ++nf) {
                    const int n = n0 + wn * 64 + nf * 16 + cl;
                    const int b = n / HWP, p = n - b * HWP;
                    outp[((size_t)b * OC + row + r) * HWP + p] = acc[mf][nf][r] + bs;
                }
            }
        }
    }
}

// ---------------------------------------------------------------------------
// MFMA windowed attention, P in registers.  r15 structure, with the
// scale+bias+mask fold replaced by one fma per element against the
// precomputed M[variant][j][i] (global, L1-resident).  sPb and the block
// __syncthreads are GONE (all remaining LDS is per-wave).
// ---------------------------------------------------------------------------
__global__ __launch_bounds__(256) void attn_mfma(const ushort* __restrict__ qkv,
                                                 const float* __restrict__ M,
                                                 ushort* __restrict__ out) {
    __shared__ __align__(16) ushort sV[4][64 * 40];   // per-wave V, then O bounce

    const int w = blockIdx.x, hg = blockIdx.y, b = blockIdx.z;
    const int wr = w >> 3, wc = w & 7;
    const int t = threadIdx.x, ww = t >> 6, l = t & 63;
    const int h = hg * 4 + ww;
    const int i15 = l & 15, g = l >> 4;
    const int hch = h * HD;
    ushort* const sVw = sV[ww];
    const float* __restrict__ Mv = M + ((((wr == 7) ? 2 : 0) | ((wc == 7) ? 1 : 0)) << 12);

    // ---- stage V (rows 49..63 zeroed), chunk-XOR swizzle on d-chunks ----
    #pragma unroll
    for (int pass = 0; pass < 4; ++pass) {
        const int e = l + pass * 64;
        const int pix = e >> 2, c8 = e & 3;
        uint4 v = make_uint4(0, 0, 0, 0);
        if (pix < WSQ) {
            const int n = b * HWP + (wr * WSZ + pix / 7) * HH + wc * WSZ + pix % 7;
            v = *(const uint4*)&qkv[(size_t)n * C3 + 2 * CC + hch + c8 * 8];
        }
        const int cst = c8 ^ ((pix >> 2) & 3);
        *(uint4*)&sVw[pix * 40 + cst * 8] = v;
    }

    // ---- Q (B-frag) and K (A-frag) direct from global, zero-padded ----
    bf16x8 qf[4], kf[4];
    #pragma unroll
    for (int it = 0; it < 4; ++it) {
        const int i = it * 16 + i15;
        U128 uq, uk;
        uq.u = make_uint4(0, 0, 0, 0);
        uk.u = make_uint4(0, 0, 0, 0);
        if (i < WSQ) {
            const int n = b * HWP + (wr * WSZ + i / 7) * HH + wc * WSZ + i % 7;
            uq.u = *(const uint4*)&qkv[(size_t)n * C3 + hch + g * 8];
            uk.u = *(const uint4*)&qkv[(size_t)n * C3 + CC + hch + g * 8];
        }
        qf[it] = uq.v;
        kf[it] = uk.v;
    }

    // ---- S^T = K·Q^T : D[j][i], lane holds i = it*16+i15, j = jt*16+4g+r ----
    f32x4 sS[4][4] = {};
    #pragma unroll
    for (int jt = 0; jt < 4; ++jt)
        #pragma unroll
        for (int it = 0; it < 4; ++it)
            sS[jt][it] = __builtin_amdgcn_mfma_f32_16x16x32_bf16(kf[jt], qf[it], sS[jt][it], 0, 0, 0);

    // ---- fold: s = s*DKS + M[j][i]  (bias+mask+padding all in M) ----
    #pragma unroll
    for (int jt = 0; jt < 4; ++jt) {
        #pragma unroll
        for (int r = 0; r < 4; ++r) {
            const float* mrow = Mv + (jt * 16 + 4 * g + r) * 64 + i15;
            #pragma unroll
            for (int it = 0; it < 4; ++it)
                sS[jt][it][r] = fmaf(sS[jt][it][r], DKS, mrow[it * 16]);
        }
    }

    // ---- softmax over j per column i: 16 in-lane + lanes l^16, l^32 ----
    #pragma unroll
    for (int it = 0; it < 4; ++it) {
        float m = -1e30f;
        #pragma unroll
        for (int jt = 0; jt < 4; ++jt)
            #pragma unroll
            for (int r = 0; r < 4; ++r) m = fmaxf(m, sS[jt][it][r]);
        m = fmaxf(m, __shfl_xor(m, 16));
        m = fmaxf(m, __shfl_xor(m, 32));
        float sum = 0.f;
        #pragma unroll
        for (int jt = 0; jt < 4; ++jt)
            #pragma unroll
            for (int r = 0; r < 4; ++r) {
                const float e2 = __expf(sS[jt][it][r] - m);
                sS[jt][it][r] = e2;
                sum += e2;
            }
        sum += __shfl_xor(sum, 16);
        sum += __shfl_xor(sum, 32);
        const float inv = 1.f / sum;
        #pragma unroll
        for (int jt = 0; jt < 4; ++jt)
            #pragma unroll
            for (int r = 0; r < 4; ++r) sS[jt][it][r] *= inv;
    }

    // ---- pack P to bf16-pair uints in registers ----
    uint plo[4][4], phi[4][4];     // [it][jt]; covers j = jt*16+4g+{0,1}/{2,3}
    #pragma unroll
    for (int it = 0; it < 4; ++it)
        #pragma unroll
        for (int jt = 0; jt < 4; ++jt) {
            plo[it][jt] = (uint)f2b(sS[jt][it][0]) | ((uint)f2b(sS[jt][it][1]) << 16);
            phi[it][jt] = (uint)f2b(sS[jt][it][2]) | ((uint)f2b(sS[jt][it][3]) << 16);
        }

    // ---- PV with shfl-assembled A-fragments ----
    const int srcLo = (2 * (g & 1)) * 16 + i15;   // source lane for u>>1 == 0
    const int srcHi = srcLo + 16;                 // source lane for u>>1 == 1
    const bool oddHalf = ((g >> 1) & 1) != 0;

    f32x4 oacc[4][2] = {};
    #pragma unroll
    for (int kt = 0; kt < 2; ++kt) {
        bf16x8 bv[2];
        #pragma unroll
        for (int nt = 0; nt < 2; ++nt) {
            U128 u;
            #pragma unroll
            for (int s = 0; s < 8; ++s) {
                const int j = kt * 32 + 8 * g + s;
                const int d = nt * 16 + i15;
                const int cp = (d >> 3) ^ ((j >> 2) & 3);
                u.us[s] = sVw[j * 40 + cp * 8 + (d & 7)];
            }
            bv[nt] = u.v;
        }
        #pragma unroll
        for (int mt = 0; mt < 4; ++mt) {
            U128 pu;
            #pragma unroll
            for (int u2 = 0; u2 < 4; ++u2) {
                const int sl = (u2 >> 1) ? srcHi : srcLo;
                const uint vE = __shfl((u2 & 1) ? phi[mt][2 * kt]     : plo[mt][2 * kt],     sl, 64);
                const uint vO = __shfl((u2 & 1) ? phi[mt][2 * kt + 1] : plo[mt][2 * kt + 1], sl, 64);
                pu.ui[u2] = oddHalf ? vO : vE;
            }
            #pragma unroll
            for (int nt = 0; nt < 2; ++nt)
                oacc[mt][nt] = __builtin_amdgcn_mfma_f32_16x16x32_bf16(pu.v, bv[nt], oacc[mt][nt], 0, 0, 0);
        }
    }

    // ---- O bounce through sVw (V dead; pad 40, chunk-XOR by (i>>2)&3) ----
    #pragma unroll
    for (int mt = 0; mt < 4; ++mt)
        #pragma unroll
        for (int nt = 0; nt < 2; ++nt)
            #pragma unroll
            for (int r = 0; r < 4; ++r) {
                const int i = mt * 16 + 4 * g + r;
                const int d = nt * 16 + i15;
                const int cp = (d >> 3) ^ ((i >> 2) & 3);
                sVw[i * 40 + cp * 8 + (d & 7)] = f2b(oacc[mt][nt][r]);
            }

    // ---- coalesced readout ----
    #pragma unroll
    for (int pass = 0; pass < 4; ++pass) {
        const int e = l + pass * 64;
        const int pix = e >> 2, c8 = e & 3;
        if (pix < WSQ) {
            const int n = b * HWP + (wr * WSZ + pix / 7) * HH + wc * WSZ + pix % 7;
            const int cp = c8 ^ ((pix >> 2) & 3);
            *(uint4*)&out[(size_t)n * CC + hch + c8 * 8] = *(const uint4*)&sVw[pix * 40 + cp * 8];
        }
    }
}

// ---------------------------------------------------------------------------
extern "C" void kernel_launch(void* const* d_in, const int* in_sizes, int n_in,
                              void* d_out, int out_size, void* d_ws, size_t ws_size,
                              hipStream_t stream) {
    const float* x      = (const float*)d_in[0];
    const float* qkv_dw = (const float*)d_in[1];
    const float* qkv_pw = (const float*)d_in[2];
    const float* qkv_pb = (const float*)d_in[3];
    const float* out_dw = (const float*)d_in[4];
    const float* out_pw = (const float*)d_in[5];
    const float* out_pb = (const float*)d_in[6];
    const float* pos    = (const float*)d_in[7];

    // ws: A [NTOT][384] | B [NTOT][1152] | wA1 [1152][384] | wA2 [384][384] | M[4][64][64] f32
    ushort* A   = (ushort*)d_ws;
    ushort* B   = A + (size_t)NTOT * CC;
    ushort* wA1 = B + (size_t)NTOT * C3;
    ushort* wA2 = wA1 + (size_t)C3 * CC;
    float*  Mw  = (float*)(wA2 + (size_t)CC * CC);

    cvt_bf16<<<(C3 * CC + 255) / 256, 256, 0, stream>>>(qkv_pw, wA1, C3 * CC);
    cvt_bf16<<<(CC * CC + 255) / 256, 256, 0, stream>>>(out_pw, wA2, CC * CC);
    prep_mask<<<64, 256, 0, stream>>>(pos, Mw);

    // 1) roll(-3) + depthwise -> A [n][384] bf16
    dconv_px<false, 3><<<dim3(14, 12, BQ), 256, 0, stream>>>(x, qkv_dw, A);
    // 2) pointwise 384->1152 -> B [n][1152] bf16  (XCD-swizzled 1-D grid)
    pconv_mfma<C3, true><<<dim3((C3 / 128) * (NTOT / 128)), 256, 0, stream>>>(A, wA1, qkv_pb, B);
    // 3) windowed attention -> A [n][384] bf16
    attn_mfma<<<dim3(NWIN, NHEAD / 4, BQ), 256, 0, stream>>>(B, Mw, A);
    // 4) roll(+3) + depthwise -> B (reused) [n][384] bf16
    dconv_px<true, 53><<<dim3(14, 12, BQ), 256, 0, stream>>>(A, out_dw, B);
    // 5) pointwise 384->384 -> d_out fp32 NCHW  (XCD-swizzled 1-D grid)
    pconv_mfma<CC, false><<<dim3((CC / 128) * (NTOT / 128)), 256, 0, stream>>>(B, wA2, out_pb, (float*)d_out);
}